// Round 17
// baseline (535.141 us; speedup 1.0000x reference)
//
#include <hip/hip_runtime.h>

// GTEA T-LSTM forward. Inputs f32, OUTPUT f32. MFMA bf16 compute.
// Pipeline:
//   prep:     f32 weights -> packed bf16, with exp-prescale folded in:
//             gate cols i/f/o (and biases) x -log2(e); g and Wd x -2log2(e)
//             -> phase B uses 2^x (exp2 builtin; raw asm TRANS op caused a
//                TRANS->VALU hazard race — builtin lets the compiler pad it).
//   sort:     counting-sort by e_len, hierarchical (ballot + 16 atomics/block)
//   pre_gemm: sft[2048][128] f32 = nf[:2048] @ eoW[0:128] + eob
//   lstm:     2048 blocks x 512 (8 waves x 16 cols), 64 edges/block, longest-first;
//             A/C double-buffered, t-loop 2x-unrolled with literal parities;
//             weights persistent in VGPRs.
//   node_mid: per node: edge GEMM (MFMA) + sparsemax + aggregate - sft -> hagg bf16
//   post_gemm: acts = relu([selfh|hagg] @ ndW + ndb); out = acts @ fcW + fcb
// ws ~= 19.4 MB

typedef unsigned short u16;
typedef unsigned int u32;
typedef unsigned long long u64;
typedef float f32x4 __attribute__((ext_vector_type(4)));
typedef short bf16x8 __attribute__((ext_vector_type(8)));

#define NDST 2048
#define EDGES 65536
#define NL2E  -1.4426950408889634f   // -log2(e)
#define NL2E2 -2.8853900817779268f   // -2*log2(e)

__device__ __forceinline__ float bf2f(u16 u) {
  union { u32 i; float f; } v; v.i = ((u32)u) << 16; return v.f;
}
__device__ __forceinline__ u16 f2bf(float f) {
  u32 x = __builtin_bit_cast(u32, f);
  u32 r = x + 0x7fffu + ((x >> 16) & 1u);
  return (u16)(r >> 16);
}
__device__ __forceinline__ u32 cvtpk2(float lo, float hi) {
  u32 r;
  asm("v_cvt_pk_bf16_f32 %0, %1, %2" : "=v"(r) : "v"(lo), "v"(hi));
  return r;
}
__device__ __forceinline__ u16 f2bf_h(float f) { return (u16)(cvtpk2(f, f) & 0xffffu); }
__device__ __forceinline__ bf16x8 ldb8(const u16* p) {
  return *reinterpret_cast<const bf16x8*>(p);
}
__device__ __forceinline__ f32x4 mfma16(bf16x8 a, bf16x8 b, f32x4 c) {
  return __builtin_amdgcn_mfma_f32_16x16x32_bf16(a, b, c, 0, 0, 0);
}
__device__ __forceinline__ float rcp_(float x) { return __builtin_amdgcn_rcpf(x); }
__device__ __forceinline__ float ex2(float x) { return __builtin_amdgcn_exp2f(x); }

// ---------------- weight prep: f32 -> packed bf16 (exp-prescaled) ----------------
__global__ __launch_bounds__(256) void prep_kernel(
    const float* __restrict__ U_m, const float* __restrict__ W_m,
    const float* __restrict__ U_a, const float* __restrict__ W_a,
    const float* __restrict__ Wd_m, const float* __restrict__ Wd_a,
    const float* __restrict__ eoW, const float* __restrict__ ndW,
    const float* __restrict__ fcW,
    u16* __restrict__ UWt_m, u16* __restrict__ UWt_a,
    u16* __restrict__ WdT_m, u16* __restrict__ WdT_a, u16* __restrict__ eoWt,
    u16* __restrict__ ndWt, u16* __restrict__ fcWt)
{
  int idx = blockIdx.x * 256 + threadIdx.x;
  if (idx < 163840) {                          // UWt: [512 cols][160 k], prescaled
    int s = idx >= 81920 ? 1 : 0;
    int i = idx - s * 81920;
    int j = i / 160, k = i % 160;
    const float* U = s ? U_a : U_m;
    const float* W = s ? W_a : W_m;
    float v = 0.f;
    if (k < 128) v = U[k * 512 + j];
    else if (k < 144) v = W[(k - 128) * 512 + j];
    v *= (j < 384) ? NL2E : NL2E2;             // i,f,o: -log2e ; g: -2log2e
    (s ? UWt_a : UWt_m)[j * 160 + k] = f2bf(v);
  } else if (idx < 196608) {                   // WdT: [128 cols][128 k], x -2log2e
    int i = idx - 163840;
    int s = i >= 16384 ? 1 : 0;
    i -= s * 16384;
    int j = i >> 7, k = i & 127;
    (s ? WdT_a : WdT_m)[j * 128 + k] = f2bf((s ? Wd_a : Wd_m)[k * 128 + j] * NL2E2);
  } else if (idx < 229376) {                   // eoWt: [128 cols][256 k]
    int i = idx - 196608;
    int j = i >> 8, k = i & 255;
    eoWt[j * 256 + k] = f2bf(eoW[k * 128 + j]);
  } else if (idx < 262144) {                   // ndWt: [128 cols][256 k]
    int i = idx - 229376;
    int j = i >> 8, k = i & 255;
    ndWt[j * 256 + k] = f2bf(ndW[k * 128 + j]);
  } else if (idx < 264192) {                   // fcWt: [16 cols][128 k]
    int i = idx - 262144;
    int j = i >> 7, k = i & 127;
    fcWt[j * 128 + k] = (j < 10) ? f2bf(fcW[k * 10 + j]) : (u16)0;
  }
}

// ---------------- counting sort by e_len (hierarchical) ----------------
__global__ __launch_bounds__(256) void hist_kernel(const int* __restrict__ elen,
                                                   int* __restrict__ cnt) {
  __shared__ int wcnt[4][16];
  const int tid = threadIdx.x;
  const int e = blockIdx.x * 256 + tid;
  const int wv = tid >> 6, ln = tid & 63;
  const int b = min(max(elen[e] - 1, 0), 15);
#pragma unroll
  for (int bb = 0; bb < 16; ++bb) {
    u64 m = __ballot(b == bb);
    if (ln == 0) wcnt[wv][bb] = __popcll(m);
  }
  __syncthreads();
  if (tid < 16)
    atomicAdd(&cnt[tid], wcnt[0][tid] + wcnt[1][tid] + wcnt[2][tid] + wcnt[3][tid]);
}
__global__ void scan_kernel(const int* __restrict__ cnt, int* __restrict__ coff) {
  if (threadIdx.x == 0 && blockIdx.x == 0) {
    int a = 0;
    for (int i = 0; i < 16; ++i) { coff[i] = a; a += cnt[i]; }
  }
}
__global__ __launch_bounds__(256) void scatter_kernel(const int* __restrict__ elen,
                                                      int* __restrict__ coff,
                                                      int* __restrict__ perm) {
  __shared__ int wcnt[4][16];
  __shared__ int base[16];
  const int tid = threadIdx.x;
  const int e = blockIdx.x * 256 + tid;
  const int wv = tid >> 6, ln = tid & 63;
  const int b = min(max(elen[e] - 1, 0), 15);
  int intrarank = 0;
#pragma unroll
  for (int bb = 0; bb < 16; ++bb) {
    u64 m = __ballot(b == bb);
    if (bb == b) intrarank = __popcll(m & ((1ull << ln) - 1ull));
    if (ln == 0) wcnt[wv][bb] = __popcll(m);
  }
  __syncthreads();
  if (tid < 16) {
    int s = wcnt[0][tid] + wcnt[1][tid] + wcnt[2][tid] + wcnt[3][tid];
    base[tid] = atomicAdd(&coff[tid], s);
  }
  __syncthreads();
  int prior = 0;
  for (int w = 0; w < wv; ++w) prior += wcnt[w][b];
  perm[base[b] + prior + intrarank] = e;
}

// ---------------- pre: sft = nf[:2048] @ eoW[0:128] + eob ----------------
__global__ __launch_bounds__(256) void pre_gemm(
    const float* __restrict__ nf, const float* __restrict__ eob,
    const u16* __restrict__ eoWt, float* __restrict__ sft)
{
  const int n0 = blockIdx.x * 32;
  const int tid = threadIdx.x;
  const int w = tid >> 6, lane = tid & 63, l15 = lane & 15, lhi = lane >> 4;
  __shared__ __align__(16) u16 A3[32 * 136];

  {
    const int row = tid >> 3, p = tid & 7;
    const float4* ph = reinterpret_cast<const float4*>(nf + (size_t)(n0 + row) * 128 + p * 16);
    float4 f0 = ph[0], f1 = ph[1], f2 = ph[2], f3 = ph[3];
    uint4 pk0, pk1;
    pk0.x = cvtpk2(f0.x, f0.y); pk0.y = cvtpk2(f0.z, f0.w);
    pk0.z = cvtpk2(f1.x, f1.y); pk0.w = cvtpk2(f1.z, f1.w);
    pk1.x = cvtpk2(f2.x, f2.y); pk1.y = cvtpk2(f2.z, f2.w);
    pk1.z = cvtpk2(f3.x, f3.y); pk1.w = cvtpk2(f3.z, f3.w);
    *reinterpret_cast<uint4*>(&A3[row * 136 + p * 16]) = pk0;
    *reinterpret_cast<uint4*>(&A3[row * 136 + p * 16 + 8]) = pk1;
  }
  __syncthreads();
  f32x4 acc[2][2];
  const int j0 = w * 32 + l15, j1 = w * 32 + 16 + l15;
  {
    float v0 = eob[j0], v1 = eob[j1];
    f32x4 t0 = {v0, v0, v0, v0}, t1 = {v1, v1, v1, v1};
    acc[0][0] = t0; acc[1][0] = t0;
    acc[0][1] = t1; acc[1][1] = t1;
  }
#pragma unroll
  for (int ks = 0; ks < 4; ++ks) {
    bf16x8 a0 = ldb8(&A3[l15 * 136 + ks * 32 + lhi * 8]);
    bf16x8 a1 = ldb8(&A3[(16 + l15) * 136 + ks * 32 + lhi * 8]);
    bf16x8 b0 = ldb8(eoWt + (size_t)j0 * 256 + ks * 32 + lhi * 8);
    bf16x8 b1 = ldb8(eoWt + (size_t)j1 * 256 + ks * 32 + lhi * 8);
    acc[0][0] = mfma16(a0, b0, acc[0][0]);
    acc[1][0] = mfma16(a1, b0, acc[1][0]);
    acc[0][1] = mfma16(a0, b1, acc[0][1]);
    acc[1][1] = mfma16(a1, b1, acc[1][1]);
  }
#pragma unroll
  for (int m = 0; m < 2; ++m)
#pragma unroll
    for (int n = 0; n < 2; ++n)
#pragma unroll
      for (int r = 0; r < 4; ++r) {
        const int row = m * 16 + lhi * 4 + r;
        const int j = w * 32 + n * 16 + l15;
        sft[(size_t)(n0 + row) * 128 + j] = acc[m][n][r];
      }
}

// ---------------- T-LSTM: 8 waves x 16 cols, 64 edges/block, 2x-unrolled steps ----------------
__global__ __launch_bounds__(512, 2)
void lstm_kernel(
    const float* __restrict__ e, const float* __restrict__ dtt,
    const float* __restrict__ b_m, const float* __restrict__ bd_m,
    const float* __restrict__ b_a, const float* __restrict__ bd_a,
    const float* __restrict__ attn,
    const int* __restrict__ elen, const int* __restrict__ perm,
    const u16* __restrict__ UWt_m, const u16* __restrict__ UWt_a,
    const u16* __restrict__ WdT_m, const u16* __restrict__ WdT_a,
    u16* __restrict__ e_out, float* __restrict__ aval_g)
{
  const int bid = blockIdx.x;
  const int sel = bid >> 10;             // 0 = message LSTM, 1 = attention LSTM
  const int edge0 = (1023 - (bid & 1023)) * 64;   // longest-first (LPT)
  const u16* UWt = sel ? UWt_a : UWt_m;
  const u16* WdT = sel ? WdT_a : WdT_m;
  const float* bg  = sel ? b_a  : b_m;
  const float* bdp = sel ? bd_a : bd_m;

  __shared__ __align__(16) u16 Abuf[2][64 * 168];
  __shared__ __align__(16) u16 Cbuf[2][64 * 136];
  __shared__ __align__(16) u16 Eo[64 * 136];
  __shared__ float dec_all[16][64];
  __shared__ int rowedge[64], elen_s[64], tmax_s;

  const int tid = threadIdx.x;
  const int ww = tid >> 6, lane = tid & 63, l15 = lane & 15, lhi = lane >> 4;
  const int j = ww * 16 + l15;
  const int srow = tid >> 3, sp = tid & 7;

  if (tid < 64) {
    int ed = perm[edge0 + tid];
    rowedge[tid] = ed;
    elen_s[tid] = min(max(elen[ed], 1), 16);
  }
  for (int i = tid; i < 2 * 64 * 168; i += 512) (&Abuf[0][0])[i] = 0;
  for (int i = tid; i < 2 * 64 * 136; i += 512) (&Cbuf[0][0])[i] = 0;
  __syncthreads();
  if (tid == 0) {
    int mx = 1;
    for (int i = 0; i < 64; ++i) mx = max(mx, elen_s[i]);
    tmax_s = mx;
  }
  for (int i = tid; i < 1024; i += 512) {
    int row = i & 63, t = i >> 6;
    dec_all[t][row] =
        1.f / logf(2.7182818284590452f + dtt[(size_t)rowedge[row] * 16 + t]);
  }
  {
    float2 e2 = *reinterpret_cast<const float2*>(e + (size_t)rowedge[srow] * 256 + sp * 2);
    *reinterpret_cast<u32*>(&Abuf[0][srow * 168 + 128 + sp * 2]) = cvtpk2(e2.x, e2.y);
  }

  // ---- persistent weight fragments (prescaled): 24 frags = 96 VGPRs/wave ----
  bf16x8 BU[5][4];
#pragma unroll
  for (int ks = 0; ks < 5; ++ks)
#pragma unroll
    for (int g = 0; g < 4; ++g)
      BU[ks][g] = ldb8(UWt + (size_t)(g * 128 + j) * 160 + ks * 32 + lhi * 8);
  bf16x8 BD[4];
#pragma unroll
  for (int ks = 0; ks < 4; ++ks)
    BD[ks] = ldb8(WdT + (size_t)j * 128 + ks * 32 + lhi * 8);
#pragma unroll
  for (int ks = 0; ks < 5; ++ks)
#pragma unroll
    for (int g = 0; g < 4; ++g)
      asm volatile("" : "+v"(BU[ks][g]));
#pragma unroll
  for (int ks = 0; ks < 4; ++ks)
    asm volatile("" : "+v"(BD[ks]));

  f32x4 bias4[4];
#pragma unroll
  for (int g = 0; g < 4; ++g) {
    float b = bg[g * 128 + j] * ((g < 3) ? NL2E : NL2E2);
    f32x4 t = {b, b, b, b};
    bias4[g] = t;
  }
  f32x4 bds4;
  {
    float b = bdp[j] * NL2E2;
    f32x4 t = {b, b, b, b};
    bds4 = t;
  }

  float cst[4][4];
#pragma unroll
  for (int mt = 0; mt < 4; ++mt)
#pragma unroll
    for (int r = 0; r < 4; ++r) cst[mt][r] = 0.f;
  __syncthreads();
  const int tmax = tmax_s;

  // one LSTM step, PB = compile-time buffer parity (read PB, write PB^1)
#define LSTM_STEP(T, PB)                                                          \
  do {                                                                            \
    const u16* Ar = Abuf[PB];                                                     \
    const u16* Cr = Cbuf[PB];                                                     \
    u16* Aw = Abuf[PB ^ 1];                                                       \
    u16* Cw = Cbuf[PB ^ 1];                                                       \
    f32x4 acc[4][4];                                                              \
    f32x4 accs[4];                                                                \
    _Pragma("unroll")                                                             \
    for (int mt = 0; mt < 4; ++mt) {                                              \
      bf16x8 a = ldb8(&Ar[(mt * 16 + l15) * 168 + lhi * 8]);                      \
      _Pragma("unroll")                                                           \
      for (int g = 0; g < 4; ++g) acc[mt][g] = mfma16(a, BU[0][g], bias4[g]);     \
    }                                                                             \
    _Pragma("unroll")                                                             \
    for (int ks = 1; ks < 5; ++ks) {                                              \
      _Pragma("unroll")                                                           \
      for (int mt = 0; mt < 4; ++mt) {                                            \
        bf16x8 a = ldb8(&Ar[(mt * 16 + l15) * 168 + ks * 32 + lhi * 8]);          \
        _Pragma("unroll")                                                         \
        for (int g = 0; g < 4; ++g) acc[mt][g] = mfma16(a, BU[ks][g], acc[mt][g]);\
      }                                                                           \
    }                                                                             \
    _Pragma("unroll")                                                             \
    for (int mt = 0; mt < 4; ++mt) {                                              \
      bf16x8 c = ldb8(&Cr[(mt * 16 + l15) * 136 + lhi * 8]);                      \
      accs[mt] = mfma16(c, BD[0], bds4);                                          \
    }                                                                             \
    _Pragma("unroll")                                                             \
    for (int ks = 1; ks < 4; ++ks) {                                              \
      _Pragma("unroll")                                                           \
      for (int mt = 0; mt < 4; ++mt) {                                            \
        bf16x8 c = ldb8(&Cr[(mt * 16 + l15) * 136 + ks * 32 + lhi * 8]);          \
        accs[mt] = mfma16(c, BD[ks], accs[mt]);                                   \
      }                                                                           \
    }                                                                             \
    float2 e2n;                                                                   \
    const bool stage_next = ((T) + 1 < tmax);                                     \
    if (stage_next)                                                               \
      e2n = *reinterpret_cast<const float2*>(                                     \
          e + (size_t)rowedge[srow] * 256 + ((T) + 1) * 16 + sp * 2);             \
    _Pragma("unroll")                                                             \
    for (int mt = 0; mt < 4; ++mt)                                                \
      _Pragma("unroll")                                                           \
      for (int r = 0; r < 4; ++r) {                                               \
        const int row = mt * 16 + lhi * 4 + r;                                    \
        float iv = rcp_(1.f + ex2(acc[mt][0][r]));                                \
        float fv = rcp_(1.f + ex2(acc[mt][1][r]));                                \
        float ov = rcp_(1.f + ex2(acc[mt][2][r]));                                \
        float gv = 2.f * rcp_(1.f + ex2(acc[mt][3][r])) - 1.f;                    \
        float cs = 2.f * rcp_(1.f + ex2(accs[mt][r])) - 1.f;                      \
        float dec = dec_all[(T)][row];                                            \
        float co = cst[mt][r];                                                    \
        float cstar = co + cs * (dec - 1.f);                                      \
        float cn = fv * cstar + iv * gv;                                          \
        float th = 2.f * rcp_(1.f + ex2(cn * NL2E2)) - 1.f;                       \
        float hn = ov * th;                                                       \
        cst[mt][r] = cn;                                                          \
        u16 hb = f2bf_h(hn);                                                      \
        Aw[row * 168 + j] = hb;                                                   \
        Cw[row * 136 + j] = f2bf_h(cn);                                           \
        if (elen_s[row] == (T) + 1) Eo[row * 136 + j] = hb;                       \
      }                                                                           \
    if (stage_next)                                                               \
      *reinterpret_cast<u32*>(&Aw[srow * 168 + 128 + sp * 2]) =                   \
          cvtpk2(e2n.x, e2n.y);                                                   \
    __syncthreads();                                                              \
  } while (0)

  for (int t = 0; t < tmax;) {
    LSTM_STEP(t, 0);
    ++t;
    if (t >= tmax) break;
    LSTM_STEP(t, 1);
    ++t;
  }
#undef LSTM_STEP

  if (sel) {   // attention logit
    if (tid < 64) {
      float s = 0.f;
      for (int k = 0; k < 128; ++k) s += bf2f(Eo[tid * 136 + k]) * attn[k];
      aval_g[rowedge[tid]] = s > 0.f ? s : 0.01f * s;
    }
  } else {     // e_out writeback
    uint4 v0 = *reinterpret_cast<const uint4*>(&Eo[srow * 136 + sp * 16]);
    uint4 v1 = *reinterpret_cast<const uint4*>(&Eo[srow * 136 + sp * 16 + 8]);
    u16* dst = e_out + (size_t)rowedge[srow] * 128 + sp * 16;
    *reinterpret_cast<uint4*>(dst) = v0;
    *reinterpret_cast<uint4*>(dst + 8) = v1;
  }
}

// ---------------- node mid: edge GEMM + sparsemax + aggregate -> hagg bf16 ----------------
__global__ __launch_bounds__(256) void node_mid(
    const float* __restrict__ nf, const u16* __restrict__ e_out,
    const float* __restrict__ aval_g, const float* __restrict__ eob,
    const int* __restrict__ srci, const u16* __restrict__ eoWt,
    const float* __restrict__ sft, u16* __restrict__ haggb)
{
  const int node = blockIdx.x;
  const int tid = threadIdx.x;
  const int ebase = node * 32;
  const int w = tid >> 6, lane = tid & 63, l15 = lane & 15, lhi = lane >> 4;

  __shared__ __align__(16) u16 A2[32 * 264];
  __shared__ __align__(16) u16 Msh[32 * 136];
  __shared__ float aval[32], zsrc[32], zs[32], redf[32], alpha_s[32];
  __shared__ int redi[32];

  {
    const int row = tid >> 3, p = tid & 7;
    const int src = srci[ebase + row];
    const float4* ph = reinterpret_cast<const float4*>(nf + (size_t)src * 128 + p * 16);
    float4 f0 = ph[0], f1 = ph[1], f2 = ph[2], f3 = ph[3];
    uint4 pk0, pk1;
    pk0.x = cvtpk2(f0.x, f0.y); pk0.y = cvtpk2(f0.z, f0.w);
    pk0.z = cvtpk2(f1.x, f1.y); pk0.w = cvtpk2(f1.z, f1.w);
    pk1.x = cvtpk2(f2.x, f2.y); pk1.y = cvtpk2(f2.z, f2.w);
    pk1.z = cvtpk2(f3.x, f3.y); pk1.w = cvtpk2(f3.z, f3.w);
    *reinterpret_cast<uint4*>(&A2[row * 264 + p * 16]) = pk0;
    *reinterpret_cast<uint4*>(&A2[row * 264 + p * 16 + 8]) = pk1;
    const u16* pe = e_out + (size_t)(ebase + row) * 128 + p * 16;
    *reinterpret_cast<uint4*>(&A2[row * 264 + 128 + p * 16]) =
        *reinterpret_cast<const uint4*>(pe);
    *reinterpret_cast<uint4*>(&A2[row * 264 + 128 + p * 16 + 8]) =
        *reinterpret_cast<const uint4*>(pe + 8);
  }
  if (tid < 32) aval[tid] = aval_g[ebase + tid];
  __syncthreads();

  {
    f32x4 eacc[2][2];
    const int j0 = w * 32 + l15, j1 = w * 32 + 16 + l15;
    {
      float v0 = eob[j0], v1 = eob[j1];
      f32x4 t0 = {v0, v0, v0, v0}, t1 = {v1, v1, v1, v1};
      eacc[0][0] = t0; eacc[1][0] = t0;
      eacc[0][1] = t1; eacc[1][1] = t1;
    }
#pragma unroll
    for (int ks = 0; ks < 8; ++ks) {
      bf16x8 a0 = ldb8(&A2[l15 * 264 + ks * 32 + lhi * 8]);
      bf16x8 a1 = ldb8(&A2[(16 + l15) * 264 + ks * 32 + lhi * 8]);
      bf16x8 b0 = ldb8(eoWt + (size_t)j0 * 256 + ks * 32 + lhi * 8);
      bf16x8 b1 = ldb8(eoWt + (size_t)j1 * 256 + ks * 32 + lhi * 8);
      eacc[0][0] = mfma16(a0, b0, eacc[0][0]);
      eacc[1][0] = mfma16(a1, b0, eacc[1][0]);
      eacc[0][1] = mfma16(a0, b1, eacc[0][1]);
      eacc[1][1] = mfma16(a1, b1, eacc[1][1]);
    }
#pragma unroll
    for (int m = 0; m < 2; ++m)
#pragma unroll
      for (int n = 0; n < 2; ++n)
#pragma unroll
        for (int r = 0; r < 4; ++r) {
          const int row = m * 16 + lhi * 4 + r;
          const int jj = w * 32 + n * 16 + l15;
          Msh[row * 136 + jj] = f2bf_h(fmaxf(eacc[m][n][r], 0.f));
        }
  }
  __syncthreads();

  if (tid < 32) {
    float mx = -1e30f;
    for (int jj = 0; jj < 32; ++jj) mx = fmaxf(mx, aval[jj]);
    float z = aval[tid] - mx;
    zsrc[tid] = z;
    int rank = 0;
    for (int jj = 0; jj < 32; ++jj) {
      float zj = aval[jj] - mx;
      rank += (zj > z) || (zj == z && jj < tid);
    }
    zs[rank] = z;
  }
  __syncthreads();
  if (tid < 32) {
    float cum = 0.f;
    for (int s = 0; s <= tid; ++s) cum += zs[s];
    float zst = zs[tid];
    bool isg = (1.f + (float)(tid + 1) * zst) > cum;
    redf[tid] = isg ? zst : 0.f;
    redi[tid] = isg ? (tid + 1) : 0;
  }
  __syncthreads();
  if (tid < 32) {
    int kk = 0; float ss = 0.f;
    for (int jj = 0; jj < 32; ++jj) { kk = max(kk, redi[jj]); ss += redf[jj]; }
    float tau = (ss - 1.f) / (float)kk;
    alpha_s[tid] = fmaxf(0.f, zsrc[tid] - tau);
  }
  __syncthreads();

  if (tid < 128) {
    float s = 0.f;
    for (int d = 0; d < 32; ++d) s += alpha_s[d] * bf2f(Msh[d * 136 + tid]);
    haggb[(size_t)node * 128 + tid] = f2bf_h(s - sft[(size_t)node * 128 + tid]);
  }
}

// ---------------- post: acts = relu([selfh|hagg]@ndW + ndb); out = acts@fcW + fcb ----------------
__global__ __launch_bounds__(256) void post_gemm(
    const float* __restrict__ nf, const u16* __restrict__ haggb,
    const float* __restrict__ ndb, const u16* __restrict__ ndWt,
    const float* __restrict__ fcb, const u16* __restrict__ fcWt,
    float* __restrict__ out)
{
  const int n0 = blockIdx.x * 32;
  const int tid = threadIdx.x;
  const int w = tid >> 6, lane = tid & 63, l15 = lane & 15, lhi = lane >> 4;
  __shared__ __align__(16) u16 A3[32 * 264];
  __shared__ __align__(16) u16 Acts[32 * 136];

  {
    const int row = tid >> 3, p = tid & 7;
    const float4* ph = reinterpret_cast<const float4*>(nf + (size_t)(n0 + row) * 128 + p * 16);
    float4 f0 = ph[0], f1 = ph[1], f2 = ph[2], f3 = ph[3];
    uint4 pk0, pk1;
    pk0.x = cvtpk2(f0.x, f0.y); pk0.y = cvtpk2(f0.z, f0.w);
    pk0.z = cvtpk2(f1.x, f1.y); pk0.w = cvtpk2(f1.z, f1.w);
    pk1.x = cvtpk2(f2.x, f2.y); pk1.y = cvtpk2(f2.z, f2.w);
    pk1.z = cvtpk2(f3.x, f3.y); pk1.w = cvtpk2(f3.z, f3.w);
    *reinterpret_cast<uint4*>(&A3[row * 264 + p * 16]) = pk0;
    *reinterpret_cast<uint4*>(&A3[row * 264 + p * 16 + 8]) = pk1;
    const u16* pg = haggb + (size_t)(n0 + row) * 128 + p * 16;
    *reinterpret_cast<uint4*>(&A3[row * 264 + 128 + p * 16]) =
        *reinterpret_cast<const uint4*>(pg);
    *reinterpret_cast<uint4*>(&A3[row * 264 + 128 + p * 16 + 8]) =
        *reinterpret_cast<const uint4*>(pg + 8);
  }
  __syncthreads();

  {
    f32x4 acc[2][2];
    const int j0 = w * 32 + l15, j1 = w * 32 + 16 + l15;
    {
      float v0 = ndb[j0], v1 = ndb[j1];
      f32x4 t0 = {v0, v0, v0, v0}, t1 = {v1, v1, v1, v1};
      acc[0][0] = t0; acc[1][0] = t0;
      acc[0][1] = t1; acc[1][1] = t1;
    }
#pragma unroll
    for (int ks = 0; ks < 8; ++ks) {
      bf16x8 a0 = ldb8(&A3[l15 * 264 + ks * 32 + lhi * 8]);
      bf16x8 a1 = ldb8(&A3[(16 + l15) * 264 + ks * 32 + lhi * 8]);
      bf16x8 b0 = ldb8(ndWt + (size_t)j0 * 256 + ks * 32 + lhi * 8);
      bf16x8 b1 = ldb8(ndWt + (size_t)j1 * 256 + ks * 32 + lhi * 8);
      acc[0][0] = mfma16(a0, b0, acc[0][0]);
      acc[1][0] = mfma16(a1, b0, acc[1][0]);
      acc[0][1] = mfma16(a0, b1, acc[0][1]);
      acc[1][1] = mfma16(a1, b1, acc[1][1]);
    }
#pragma unroll
    for (int m = 0; m < 2; ++m)
#pragma unroll
      for (int n = 0; n < 2; ++n)
#pragma unroll
        for (int r = 0; r < 4; ++r) {
          const int row = m * 16 + lhi * 4 + r;
          const int jj = w * 32 + n * 16 + l15;
          Acts[row * 136 + jj] = f2bf_h(fmaxf(acc[m][n][r], 0.f));
        }
  }
  __syncthreads();

  if (w < 2) {
    const int m = w;
    f32x4 acc1;
    {
      float v = (l15 < 10) ? fcb[l15] : 0.f;
      f32x4 t = {v, v, v, v};
      acc1 = t;
    }
#pragma unroll
    for (int ks = 0; ks < 4; ++ks) {
      bf16x8 a = ldb8(&Acts[(m * 16 + l15) * 136 + ks * 32 + lhi * 8]);
      bf16x8 b = ldb8(fcWt + (size_t)l15 * 128 + ks * 32 + lhi * 8);
      acc1 = mfma16(a, b, acc1);
    }
    if (l15 < 10) {
#pragma unroll
      for (int r = 0; r < 4; ++r) {
        const int row = m * 16 + lhi * 4 + r;
        out[(size_t)(n0 + row) * 10 + l15] = acc1[r];
      }
    }
  }
}

extern "C" void kernel_launch(void* const* d_in, const int* in_sizes, int n_in,
                              void* d_out, int out_size, void* d_ws, size_t ws_size,
                              hipStream_t stream)
{
  const float* nf   = (const float*)d_in[0];
  const float* e    = (const float*)d_in[1];
  const float* dtt  = (const float*)d_in[2];
  const float* W_m  = (const float*)d_in[3];
  const float* U_m  = (const float*)d_in[4];
  const float* b_m  = (const float*)d_in[5];
  const float* Wd_m = (const float*)d_in[6];
  const float* bd_m = (const float*)d_in[7];
  const float* W_a  = (const float*)d_in[8];
  const float* U_a  = (const float*)d_in[9];
  const float* b_a  = (const float*)d_in[10];
  const float* Wd_a = (const float*)d_in[11];
  const float* bd_a = (const float*)d_in[12];
  const float* attn = (const float*)d_in[13];
  const float* eoW  = (const float*)d_in[14];
  const float* eob  = (const float*)d_in[15];
  const float* ndW  = (const float*)d_in[16];
  const float* ndb  = (const float*)d_in[17];
  const float* fcW  = (const float*)d_in[18];
  const float* fcb  = (const float*)d_in[19];
  const int* elen = (const int*)d_in[20];
  const int* srci = (const int*)d_in[21];

  char* ws = (char*)d_ws;
  u16* UWt_m  = (u16*)(ws + 0);
  u16* UWt_a  = (u16*)(ws + 163840);
  u16* WdT_m  = (u16*)(ws + 327680);
  u16* WdT_a  = (u16*)(ws + 360448);
  u16* eoWt   = (u16*)(ws + 393216);          // ends 458752
  u16* e_out  = (u16*)(ws + 458752);          // 16 MB
  float* aval = (float*)(ws + 17235968);      // 256 KB
  int* perm   = (int*)(ws + 17498112);        // 256 KB
  int* cnt    = (int*)(ws + 17760256);
  int* coff   = (int*)(ws + 17760320);
  u16* ndWt   = (u16*)(ws + 17760384);        // 64 KB
  u16* fcWt   = (u16*)(ws + 17825920);        // 4 KB
  float* sft  = (float*)(ws + 17830016);      // 1 MB
  u16* haggb  = (u16*)(ws + 18878592);        // 512 KB

  hipMemsetAsync(cnt, 0, 64, stream);
  prep_kernel<<<1032, 256, 0, stream>>>(U_m, W_m, U_a, W_a, Wd_m, Wd_a, eoW, ndW, fcW,
                                        UWt_m, UWt_a, WdT_m, WdT_a, eoWt, ndWt, fcWt);
  hist_kernel<<<EDGES / 256, 256, 0, stream>>>(elen, cnt);
  scan_kernel<<<1, 1, 0, stream>>>(cnt, coff);
  scatter_kernel<<<EDGES / 256, 256, 0, stream>>>(elen, coff, perm);
  pre_gemm<<<NDST / 32, 256, 0, stream>>>(nf, eob, eoWt, sft);
  lstm_kernel<<<2048, 512, 0, stream>>>(e, dtt, b_m, bd_m, b_a, bd_a, attn,
                                        elen, perm, UWt_m, UWt_a, WdT_m, WdT_a,
                                        e_out, aval);
  node_mid<<<NDST, 256, 0, stream>>>(nf, e_out, aval, eob, srci, eoWt, sft, haggb);
  post_gemm<<<NDST / 32, 256, 0, stream>>>(nf, haggb, ndb, ndWt, fcb, fcWt,
                                           (float*)d_out);
}

// Round 18
// 467.385 us; speedup vs baseline: 1.1450x; 1.1450x over previous
//
#include <hip/hip_runtime.h>

// GTEA T-LSTM forward. Inputs f32, OUTPUT f32. MFMA bf16 compute.
// Pipeline:
//   prep:     f32 weights -> packed bf16, exp-prescale folded in:
//             gate cols i/f/o (and biases) x -log2(e); g and Wd x -2log2(e)
//             -> phase B uses 2^x via __builtin_amdgcn_exp2f (compiler handles
//                the TRANS->VALU hazard; raw asm raced, round 16).
//   sort:     counting-sort by e_len, hierarchical (ballot + 16 atomics/block)
//   pre_gemm: sft[2048][128] f32 = nf[:2048] @ eoW[0:128] + eob
//   lstm:     2048 blocks x 512 (8 waves x 16 cols), 64 edges/block, longest-first;
//             A/C double-buffered, SINGLE-body t-loop (2x-unroll spilled ~190MB
//             scratch/dispatch, round 17); weights persistent in VGPRs.
//   node_mid: per node: edge GEMM (MFMA) + sparsemax + aggregate - sft -> hagg bf16
//   post_gemm: acts = relu([selfh|hagg] @ ndW + ndb); out = acts @ fcW + fcb
// ws ~= 19.4 MB

typedef unsigned short u16;
typedef unsigned int u32;
typedef unsigned long long u64;
typedef float f32x4 __attribute__((ext_vector_type(4)));
typedef short bf16x8 __attribute__((ext_vector_type(8)));

#define NDST 2048
#define EDGES 65536
#define NL2E  -1.4426950408889634f   // -log2(e)
#define NL2E2 -2.8853900817779268f   // -2*log2(e)

__device__ __forceinline__ float bf2f(u16 u) {
  union { u32 i; float f; } v; v.i = ((u32)u) << 16; return v.f;
}
__device__ __forceinline__ u16 f2bf(float f) {
  u32 x = __builtin_bit_cast(u32, f);
  u32 r = x + 0x7fffu + ((x >> 16) & 1u);
  return (u16)(r >> 16);
}
__device__ __forceinline__ u32 cvtpk2(float lo, float hi) {
  u32 r;
  asm("v_cvt_pk_bf16_f32 %0, %1, %2" : "=v"(r) : "v"(lo), "v"(hi));
  return r;
}
__device__ __forceinline__ u16 f2bf_h(float f) { return (u16)(cvtpk2(f, f) & 0xffffu); }
__device__ __forceinline__ bf16x8 ldb8(const u16* p) {
  return *reinterpret_cast<const bf16x8*>(p);
}
__device__ __forceinline__ f32x4 mfma16(bf16x8 a, bf16x8 b, f32x4 c) {
  return __builtin_amdgcn_mfma_f32_16x16x32_bf16(a, b, c, 0, 0, 0);
}
__device__ __forceinline__ float rcp_(float x) { return __builtin_amdgcn_rcpf(x); }
__device__ __forceinline__ float ex2(float x) { return __builtin_amdgcn_exp2f(x); }

// ---------------- weight prep: f32 -> packed bf16 (exp-prescaled) ----------------
__global__ __launch_bounds__(256) void prep_kernel(
    const float* __restrict__ U_m, const float* __restrict__ W_m,
    const float* __restrict__ U_a, const float* __restrict__ W_a,
    const float* __restrict__ Wd_m, const float* __restrict__ Wd_a,
    const float* __restrict__ eoW, const float* __restrict__ ndW,
    const float* __restrict__ fcW,
    u16* __restrict__ UWt_m, u16* __restrict__ UWt_a,
    u16* __restrict__ WdT_m, u16* __restrict__ WdT_a, u16* __restrict__ eoWt,
    u16* __restrict__ ndWt, u16* __restrict__ fcWt)
{
  int idx = blockIdx.x * 256 + threadIdx.x;
  if (idx < 163840) {                          // UWt: [512 cols][160 k], prescaled
    int s = idx >= 81920 ? 1 : 0;
    int i = idx - s * 81920;
    int j = i / 160, k = i % 160;
    const float* U = s ? U_a : U_m;
    const float* W = s ? W_a : W_m;
    float v = 0.f;
    if (k < 128) v = U[k * 512 + j];
    else if (k < 144) v = W[(k - 128) * 512 + j];
    v *= (j < 384) ? NL2E : NL2E2;             // i,f,o: -log2e ; g: -2log2e
    (s ? UWt_a : UWt_m)[j * 160 + k] = f2bf(v);
  } else if (idx < 196608) {                   // WdT: [128 cols][128 k], x -2log2e
    int i = idx - 163840;
    int s = i >= 16384 ? 1 : 0;
    i -= s * 16384;
    int j = i >> 7, k = i & 127;
    (s ? WdT_a : WdT_m)[j * 128 + k] = f2bf((s ? Wd_a : Wd_m)[k * 128 + j] * NL2E2);
  } else if (idx < 229376) {                   // eoWt: [128 cols][256 k]
    int i = idx - 196608;
    int j = i >> 8, k = i & 255;
    eoWt[j * 256 + k] = f2bf(eoW[k * 128 + j]);
  } else if (idx < 262144) {                   // ndWt: [128 cols][256 k]
    int i = idx - 229376;
    int j = i >> 8, k = i & 255;
    ndWt[j * 256 + k] = f2bf(ndW[k * 128 + j]);
  } else if (idx < 264192) {                   // fcWt: [16 cols][128 k]
    int i = idx - 262144;
    int j = i >> 7, k = i & 127;
    fcWt[j * 128 + k] = (j < 10) ? f2bf(fcW[k * 10 + j]) : (u16)0;
  }
}

// ---------------- counting sort by e_len (hierarchical) ----------------
__global__ __launch_bounds__(256) void hist_kernel(const int* __restrict__ elen,
                                                   int* __restrict__ cnt) {
  __shared__ int wcnt[4][16];
  const int tid = threadIdx.x;
  const int e = blockIdx.x * 256 + tid;
  const int wv = tid >> 6, ln = tid & 63;
  const int b = min(max(elen[e] - 1, 0), 15);
#pragma unroll
  for (int bb = 0; bb < 16; ++bb) {
    u64 m = __ballot(b == bb);
    if (ln == 0) wcnt[wv][bb] = __popcll(m);
  }
  __syncthreads();
  if (tid < 16)
    atomicAdd(&cnt[tid], wcnt[0][tid] + wcnt[1][tid] + wcnt[2][tid] + wcnt[3][tid]);
}
__global__ void scan_kernel(const int* __restrict__ cnt, int* __restrict__ coff) {
  if (threadIdx.x == 0 && blockIdx.x == 0) {
    int a = 0;
    for (int i = 0; i < 16; ++i) { coff[i] = a; a += cnt[i]; }
  }
}
__global__ __launch_bounds__(256) void scatter_kernel(const int* __restrict__ elen,
                                                      int* __restrict__ coff,
                                                      int* __restrict__ perm) {
  __shared__ int wcnt[4][16];
  __shared__ int base[16];
  const int tid = threadIdx.x;
  const int e = blockIdx.x * 256 + tid;
  const int wv = tid >> 6, ln = tid & 63;
  const int b = min(max(elen[e] - 1, 0), 15);
  int intrarank = 0;
#pragma unroll
  for (int bb = 0; bb < 16; ++bb) {
    u64 m = __ballot(b == bb);
    if (bb == b) intrarank = __popcll(m & ((1ull << ln) - 1ull));
    if (ln == 0) wcnt[wv][bb] = __popcll(m);
  }
  __syncthreads();
  if (tid < 16) {
    int s = wcnt[0][tid] + wcnt[1][tid] + wcnt[2][tid] + wcnt[3][tid];
    base[tid] = atomicAdd(&coff[tid], s);
  }
  __syncthreads();
  int prior = 0;
  for (int w = 0; w < wv; ++w) prior += wcnt[w][b];
  perm[base[b] + prior + intrarank] = e;
}

// ---------------- pre: sft = nf[:2048] @ eoW[0:128] + eob ----------------
__global__ __launch_bounds__(256) void pre_gemm(
    const float* __restrict__ nf, const float* __restrict__ eob,
    const u16* __restrict__ eoWt, float* __restrict__ sft)
{
  const int n0 = blockIdx.x * 32;
  const int tid = threadIdx.x;
  const int w = tid >> 6, lane = tid & 63, l15 = lane & 15, lhi = lane >> 4;
  __shared__ __align__(16) u16 A3[32 * 136];

  {
    const int row = tid >> 3, p = tid & 7;
    const float4* ph = reinterpret_cast<const float4*>(nf + (size_t)(n0 + row) * 128 + p * 16);
    float4 f0 = ph[0], f1 = ph[1], f2 = ph[2], f3 = ph[3];
    uint4 pk0, pk1;
    pk0.x = cvtpk2(f0.x, f0.y); pk0.y = cvtpk2(f0.z, f0.w);
    pk0.z = cvtpk2(f1.x, f1.y); pk0.w = cvtpk2(f1.z, f1.w);
    pk1.x = cvtpk2(f2.x, f2.y); pk1.y = cvtpk2(f2.z, f2.w);
    pk1.z = cvtpk2(f3.x, f3.y); pk1.w = cvtpk2(f3.z, f3.w);
    *reinterpret_cast<uint4*>(&A3[row * 136 + p * 16]) = pk0;
    *reinterpret_cast<uint4*>(&A3[row * 136 + p * 16 + 8]) = pk1;
  }
  __syncthreads();
  f32x4 acc[2][2];
  const int j0 = w * 32 + l15, j1 = w * 32 + 16 + l15;
  {
    float v0 = eob[j0], v1 = eob[j1];
    f32x4 t0 = {v0, v0, v0, v0}, t1 = {v1, v1, v1, v1};
    acc[0][0] = t0; acc[1][0] = t0;
    acc[0][1] = t1; acc[1][1] = t1;
  }
#pragma unroll
  for (int ks = 0; ks < 4; ++ks) {
    bf16x8 a0 = ldb8(&A3[l15 * 136 + ks * 32 + lhi * 8]);
    bf16x8 a1 = ldb8(&A3[(16 + l15) * 136 + ks * 32 + lhi * 8]);
    bf16x8 b0 = ldb8(eoWt + (size_t)j0 * 256 + ks * 32 + lhi * 8);
    bf16x8 b1 = ldb8(eoWt + (size_t)j1 * 256 + ks * 32 + lhi * 8);
    acc[0][0] = mfma16(a0, b0, acc[0][0]);
    acc[1][0] = mfma16(a1, b0, acc[1][0]);
    acc[0][1] = mfma16(a0, b1, acc[0][1]);
    acc[1][1] = mfma16(a1, b1, acc[1][1]);
  }
#pragma unroll
  for (int m = 0; m < 2; ++m)
#pragma unroll
    for (int n = 0; n < 2; ++n)
#pragma unroll
      for (int r = 0; r < 4; ++r) {
        const int row = m * 16 + lhi * 4 + r;
        const int j = w * 32 + n * 16 + l15;
        sft[(size_t)(n0 + row) * 128 + j] = acc[m][n][r];
      }
}

// ---------------- T-LSTM: 8 waves x 16 cols, 64 edges/block, single-body loop ----------------
__global__ __launch_bounds__(512, 2)
void lstm_kernel(
    const float* __restrict__ e, const float* __restrict__ dtt,
    const float* __restrict__ b_m, const float* __restrict__ bd_m,
    const float* __restrict__ b_a, const float* __restrict__ bd_a,
    const float* __restrict__ attn,
    const int* __restrict__ elen, const int* __restrict__ perm,
    const u16* __restrict__ UWt_m, const u16* __restrict__ UWt_a,
    const u16* __restrict__ WdT_m, const u16* __restrict__ WdT_a,
    u16* __restrict__ e_out, float* __restrict__ aval_g)
{
  const int bid = blockIdx.x;
  const int sel = bid >> 10;             // 0 = message LSTM, 1 = attention LSTM
  const int edge0 = (1023 - (bid & 1023)) * 64;   // longest-first (LPT)
  const u16* UWt = sel ? UWt_a : UWt_m;
  const u16* WdT = sel ? WdT_a : WdT_m;
  const float* bg  = sel ? b_a  : b_m;
  const float* bdp = sel ? bd_a : bd_m;

  __shared__ __align__(16) u16 Abuf[2][64 * 168];
  __shared__ __align__(16) u16 Cbuf[2][64 * 136];
  __shared__ __align__(16) u16 Eo[64 * 136];
  __shared__ float dec_all[16][64];
  __shared__ int rowedge[64], elen_s[64], tmax_s;

  const int tid = threadIdx.x;
  const int ww = tid >> 6, lane = tid & 63, l15 = lane & 15, lhi = lane >> 4;
  const int j = ww * 16 + l15;
  const int srow = tid >> 3, sp = tid & 7;

  if (tid < 64) {
    int ed = perm[edge0 + tid];
    rowedge[tid] = ed;
    elen_s[tid] = min(max(elen[ed], 1), 16);
  }
  for (int i = tid; i < 2 * 64 * 168; i += 512) (&Abuf[0][0])[i] = 0;
  for (int i = tid; i < 2 * 64 * 136; i += 512) (&Cbuf[0][0])[i] = 0;
  __syncthreads();
  if (tid == 0) {
    int mx = 1;
    for (int i = 0; i < 64; ++i) mx = max(mx, elen_s[i]);
    tmax_s = mx;
  }
  for (int i = tid; i < 1024; i += 512) {
    int row = i & 63, t = i >> 6;
    dec_all[t][row] =
        1.f / logf(2.7182818284590452f + dtt[(size_t)rowedge[row] * 16 + t]);
  }
  {
    float2 e2 = *reinterpret_cast<const float2*>(e + (size_t)rowedge[srow] * 256 + sp * 2);
    *reinterpret_cast<u32*>(&Abuf[0][srow * 168 + 128 + sp * 2]) = cvtpk2(e2.x, e2.y);
  }

  // ---- persistent weight fragments (prescaled): 24 frags = 96 VGPRs/wave ----
  bf16x8 BU[5][4];
#pragma unroll
  for (int ks = 0; ks < 5; ++ks)
#pragma unroll
    for (int g = 0; g < 4; ++g)
      BU[ks][g] = ldb8(UWt + (size_t)(g * 128 + j) * 160 + ks * 32 + lhi * 8);
  bf16x8 BD[4];
#pragma unroll
  for (int ks = 0; ks < 4; ++ks)
    BD[ks] = ldb8(WdT + (size_t)j * 128 + ks * 32 + lhi * 8);
#pragma unroll
  for (int ks = 0; ks < 5; ++ks)
#pragma unroll
    for (int g = 0; g < 4; ++g)
      asm volatile("" : "+v"(BU[ks][g]));
#pragma unroll
  for (int ks = 0; ks < 4; ++ks)
    asm volatile("" : "+v"(BD[ks]));

  f32x4 bias4[4];
#pragma unroll
  for (int g = 0; g < 4; ++g) {
    float b = bg[g * 128 + j] * ((g < 3) ? NL2E : NL2E2);
    f32x4 t = {b, b, b, b};
    bias4[g] = t;
  }
  f32x4 bds4;
  {
    float b = bdp[j] * NL2E2;
    f32x4 t = {b, b, b, b};
    bds4 = t;
  }

  float cst[4][4];
#pragma unroll
  for (int mt = 0; mt < 4; ++mt)
#pragma unroll
    for (int r = 0; r < 4; ++r) cst[mt][r] = 0.f;
  __syncthreads();
  const int tmax = tmax_s;

  for (int t = 0; t < tmax; ++t) {
    const u16* Ar = Abuf[t & 1];
    const u16* Cr = Cbuf[t & 1];
    u16* Aw = Abuf[(t + 1) & 1];
    u16* Cw = Cbuf[(t + 1) & 1];

    f32x4 acc[4][4];
    f32x4 accs[4];
#pragma unroll
    for (int mt = 0; mt < 4; ++mt) {
      bf16x8 a = ldb8(&Ar[(mt * 16 + l15) * 168 + lhi * 8]);
#pragma unroll
      for (int g = 0; g < 4; ++g)
        acc[mt][g] = mfma16(a, BU[0][g], bias4[g]);
    }
#pragma unroll
    for (int ks = 1; ks < 5; ++ks) {
#pragma unroll
      for (int mt = 0; mt < 4; ++mt) {
        bf16x8 a = ldb8(&Ar[(mt * 16 + l15) * 168 + ks * 32 + lhi * 8]);
#pragma unroll
        for (int g = 0; g < 4; ++g)
          acc[mt][g] = mfma16(a, BU[ks][g], acc[mt][g]);
      }
    }
#pragma unroll
    for (int mt = 0; mt < 4; ++mt) {
      bf16x8 c = ldb8(&Cr[(mt * 16 + l15) * 136 + lhi * 8]);
      accs[mt] = mfma16(c, BD[0], bds4);
    }
#pragma unroll
    for (int ks = 1; ks < 4; ++ks) {
#pragma unroll
      for (int mt = 0; mt < 4; ++mt) {
        bf16x8 c = ldb8(&Cr[(mt * 16 + l15) * 136 + ks * 32 + lhi * 8]);
        accs[mt] = mfma16(c, BD[ks], accs[mt]);
      }
    }
    // NO barrier: phase B writes the other buffer.

    // T14 split: issue next e_t load now, LDS-write after phase B
    float2 e2n;
    const bool stage_next = (t + 1 < tmax);
    if (stage_next)
      e2n = *reinterpret_cast<const float2*>(
          e + (size_t)rowedge[srow] * 256 + (t + 1) * 16 + sp * 2);

#pragma unroll
    for (int mt = 0; mt < 4; ++mt)
#pragma unroll
      for (int r = 0; r < 4; ++r) {
        const int row = mt * 16 + lhi * 4 + r;
        float iv = rcp_(1.f + ex2(acc[mt][0][r]));
        float fv = rcp_(1.f + ex2(acc[mt][1][r]));
        float ov = rcp_(1.f + ex2(acc[mt][2][r]));
        float gv = 2.f * rcp_(1.f + ex2(acc[mt][3][r])) - 1.f;
        float cs = 2.f * rcp_(1.f + ex2(accs[mt][r])) - 1.f;
        float dec = dec_all[t][row];
        float co = cst[mt][r];
        float cstar = co + cs * (dec - 1.f);   // c - c_s + c_s*dec
        float cn = fv * cstar + iv * gv;
        float th = 2.f * rcp_(1.f + ex2(cn * NL2E2)) - 1.f;
        float hn = ov * th;
        cst[mt][r] = cn;
        u16 hb = f2bf_h(hn);
        Aw[row * 168 + j] = hb;
        Cw[row * 136 + j] = f2bf_h(cn);
        if (elen_s[row] == t + 1) Eo[row * 136 + j] = hb;
      }
    if (stage_next)
      *reinterpret_cast<u32*>(&Aw[srow * 168 + 128 + sp * 2]) = cvtpk2(e2n.x, e2n.y);
    __syncthreads();   // single barrier per step
  }

  if (sel) {   // attention logit
    if (tid < 64) {
      float s = 0.f;
      for (int k = 0; k < 128; ++k) s += bf2f(Eo[tid * 136 + k]) * attn[k];
      aval_g[rowedge[tid]] = s > 0.f ? s : 0.01f * s;
    }
  } else {     // e_out writeback
    uint4 v0 = *reinterpret_cast<const uint4*>(&Eo[srow * 136 + sp * 16]);
    uint4 v1 = *reinterpret_cast<const uint4*>(&Eo[srow * 136 + sp * 16 + 8]);
    u16* dst = e_out + (size_t)rowedge[srow] * 128 + sp * 16;
    *reinterpret_cast<uint4*>(dst) = v0;
    *reinterpret_cast<uint4*>(dst + 8) = v1;
  }
}

// ---------------- node mid: edge GEMM + sparsemax + aggregate -> hagg bf16 ----------------
__global__ __launch_bounds__(256) void node_mid(
    const float* __restrict__ nf, const u16* __restrict__ e_out,
    const float* __restrict__ aval_g, const float* __restrict__ eob,
    const int* __restrict__ srci, const u16* __restrict__ eoWt,
    const float* __restrict__ sft, u16* __restrict__ haggb)
{
  const int node = blockIdx.x;
  const int tid = threadIdx.x;
  const int ebase = node * 32;
  const int w = tid >> 6, lane = tid & 63, l15 = lane & 15, lhi = lane >> 4;

  __shared__ __align__(16) u16 A2[32 * 264];
  __shared__ __align__(16) u16 Msh[32 * 136];
  __shared__ float aval[32], zsrc[32], zs[32], redf[32], alpha_s[32];
  __shared__ int redi[32];

  {
    const int row = tid >> 3, p = tid & 7;
    const int src = srci[ebase + row];
    const float4* ph = reinterpret_cast<const float4*>(nf + (size_t)src * 128 + p * 16);
    float4 f0 = ph[0], f1 = ph[1], f2 = ph[2], f3 = ph[3];
    uint4 pk0, pk1;
    pk0.x = cvtpk2(f0.x, f0.y); pk0.y = cvtpk2(f0.z, f0.w);
    pk0.z = cvtpk2(f1.x, f1.y); pk0.w = cvtpk2(f1.z, f1.w);
    pk1.x = cvtpk2(f2.x, f2.y); pk1.y = cvtpk2(f2.z, f2.w);
    pk1.z = cvtpk2(f3.x, f3.y); pk1.w = cvtpk2(f3.z, f3.w);
    *reinterpret_cast<uint4*>(&A2[row * 264 + p * 16]) = pk0;
    *reinterpret_cast<uint4*>(&A2[row * 264 + p * 16 + 8]) = pk1;
    const u16* pe = e_out + (size_t)(ebase + row) * 128 + p * 16;
    *reinterpret_cast<uint4*>(&A2[row * 264 + 128 + p * 16]) =
        *reinterpret_cast<const uint4*>(pe);
    *reinterpret_cast<uint4*>(&A2[row * 264 + 128 + p * 16 + 8]) =
        *reinterpret_cast<const uint4*>(pe + 8);
  }
  if (tid < 32) aval[tid] = aval_g[ebase + tid];
  __syncthreads();

  {
    f32x4 eacc[2][2];
    const int j0 = w * 32 + l15, j1 = w * 32 + 16 + l15;
    {
      float v0 = eob[j0], v1 = eob[j1];
      f32x4 t0 = {v0, v0, v0, v0}, t1 = {v1, v1, v1, v1};
      eacc[0][0] = t0; eacc[1][0] = t0;
      eacc[0][1] = t1; eacc[1][1] = t1;
    }
#pragma unroll
    for (int ks = 0; ks < 8; ++ks) {
      bf16x8 a0 = ldb8(&A2[l15 * 264 + ks * 32 + lhi * 8]);
      bf16x8 a1 = ldb8(&A2[(16 + l15) * 264 + ks * 32 + lhi * 8]);
      bf16x8 b0 = ldb8(eoWt + (size_t)j0 * 256 + ks * 32 + lhi * 8);
      bf16x8 b1 = ldb8(eoWt + (size_t)j1 * 256 + ks * 32 + lhi * 8);
      eacc[0][0] = mfma16(a0, b0, eacc[0][0]);
      eacc[1][0] = mfma16(a1, b0, eacc[1][0]);
      eacc[0][1] = mfma16(a0, b1, eacc[0][1]);
      eacc[1][1] = mfma16(a1, b1, eacc[1][1]);
    }
#pragma unroll
    for (int m = 0; m < 2; ++m)
#pragma unroll
      for (int n = 0; n < 2; ++n)
#pragma unroll
        for (int r = 0; r < 4; ++r) {
          const int row = m * 16 + lhi * 4 + r;
          const int jj = w * 32 + n * 16 + l15;
          Msh[row * 136 + jj] = f2bf_h(fmaxf(eacc[m][n][r], 0.f));
        }
  }
  __syncthreads();

  if (tid < 32) {
    float mx = -1e30f;
    for (int jj = 0; jj < 32; ++jj) mx = fmaxf(mx, aval[jj]);
    float z = aval[tid] - mx;
    zsrc[tid] = z;
    int rank = 0;
    for (int jj = 0; jj < 32; ++jj) {
      float zj = aval[jj] - mx;
      rank += (zj > z) || (zj == z && jj < tid);
    }
    zs[rank] = z;
  }
  __syncthreads();
  if (tid < 32) {
    float cum = 0.f;
    for (int s = 0; s <= tid; ++s) cum += zs[s];
    float zst = zs[tid];
    bool isg = (1.f + (float)(tid + 1) * zst) > cum;
    redf[tid] = isg ? zst : 0.f;
    redi[tid] = isg ? (tid + 1) : 0;
  }
  __syncthreads();
  if (tid < 32) {
    int kk = 0; float ss = 0.f;
    for (int jj = 0; jj < 32; ++jj) { kk = max(kk, redi[jj]); ss += redf[jj]; }
    float tau = (ss - 1.f) / (float)kk;
    alpha_s[tid] = fmaxf(0.f, zsrc[tid] - tau);
  }
  __syncthreads();

  if (tid < 128) {
    float s = 0.f;
    for (int d = 0; d < 32; ++d) s += alpha_s[d] * bf2f(Msh[d * 136 + tid]);
    haggb[(size_t)node * 128 + tid] = f2bf_h(s - sft[(size_t)node * 128 + tid]);
  }
}

// ---------------- post: acts = relu([selfh|hagg]@ndW + ndb); out = acts@fcW + fcb ----------------
__global__ __launch_bounds__(256) void post_gemm(
    const float* __restrict__ nf, const u16* __restrict__ haggb,
    const float* __restrict__ ndb, const u16* __restrict__ ndWt,
    const float* __restrict__ fcb, const u16* __restrict__ fcWt,
    float* __restrict__ out)
{
  const int n0 = blockIdx.x * 32;
  const int tid = threadIdx.x;
  const int w = tid >> 6, lane = tid & 63, l15 = lane & 15, lhi = lane >> 4;
  __shared__ __align__(16) u16 A3[32 * 264];
  __shared__ __align__(16) u16 Acts[32 * 136];

  {
    const int row = tid >> 3, p = tid & 7;
    const float4* ph = reinterpret_cast<const float4*>(nf + (size_t)(n0 + row) * 128 + p * 16);
    float4 f0 = ph[0], f1 = ph[1], f2 = ph[2], f3 = ph[3];
    uint4 pk0, pk1;
    pk0.x = cvtpk2(f0.x, f0.y); pk0.y = cvtpk2(f0.z, f0.w);
    pk0.z = cvtpk2(f1.x, f1.y); pk0.w = cvtpk2(f1.z, f1.w);
    pk1.x = cvtpk2(f2.x, f2.y); pk1.y = cvtpk2(f2.z, f2.w);
    pk1.z = cvtpk2(f3.x, f3.y); pk1.w = cvtpk2(f3.z, f3.w);
    *reinterpret_cast<uint4*>(&A3[row * 264 + p * 16]) = pk0;
    *reinterpret_cast<uint4*>(&A3[row * 264 + p * 16 + 8]) = pk1;
    const u16* pg = haggb + (size_t)(n0 + row) * 128 + p * 16;
    *reinterpret_cast<uint4*>(&A3[row * 264 + 128 + p * 16]) =
        *reinterpret_cast<const uint4*>(pg);
    *reinterpret_cast<uint4*>(&A3[row * 264 + 128 + p * 16 + 8]) =
        *reinterpret_cast<const uint4*>(pg + 8);
  }
  __syncthreads();

  {
    f32x4 acc[2][2];
    const int j0 = w * 32 + l15, j1 = w * 32 + 16 + l15;
    {
      float v0 = ndb[j0], v1 = ndb[j1];
      f32x4 t0 = {v0, v0, v0, v0}, t1 = {v1, v1, v1, v1};
      acc[0][0] = t0; acc[1][0] = t0;
      acc[0][1] = t1; acc[1][1] = t1;
    }
#pragma unroll
    for (int ks = 0; ks < 8; ++ks) {
      bf16x8 a0 = ldb8(&A3[l15 * 264 + ks * 32 + lhi * 8]);
      bf16x8 a1 = ldb8(&A3[(16 + l15) * 264 + ks * 32 + lhi * 8]);
      bf16x8 b0 = ldb8(ndWt + (size_t)j0 * 256 + ks * 32 + lhi * 8);
      bf16x8 b1 = ldb8(ndWt + (size_t)j1 * 256 + ks * 32 + lhi * 8);
      acc[0][0] = mfma16(a0, b0, acc[0][0]);
      acc[1][0] = mfma16(a1, b0, acc[1][0]);
      acc[0][1] = mfma16(a0, b1, acc[0][1]);
      acc[1][1] = mfma16(a1, b1, acc[1][1]);
    }
#pragma unroll
    for (int m = 0; m < 2; ++m)
#pragma unroll
      for (int n = 0; n < 2; ++n)
#pragma unroll
        for (int r = 0; r < 4; ++r) {
          const int row = m * 16 + lhi * 4 + r;
          const int jj = w * 32 + n * 16 + l15;
          Acts[row * 136 + jj] = f2bf_h(fmaxf(acc[m][n][r], 0.f));
        }
  }
  __syncthreads();

  if (w < 2) {
    const int m = w;
    f32x4 acc1;
    {
      float v = (l15 < 10) ? fcb[l15] : 0.f;
      f32x4 t = {v, v, v, v};
      acc1 = t;
    }
#pragma unroll
    for (int ks = 0; ks < 4; ++ks) {
      bf16x8 a = ldb8(&Acts[(m * 16 + l15) * 136 + ks * 32 + lhi * 8]);
      bf16x8 b = ldb8(fcWt + (size_t)l15 * 128 + ks * 32 + lhi * 8);
      acc1 = mfma16(a, b, acc1);
    }
    if (l15 < 10) {
#pragma unroll
      for (int r = 0; r < 4; ++r) {
        const int row = m * 16 + lhi * 4 + r;
        out[(size_t)(n0 + row) * 10 + l15] = acc1[r];
      }
    }
  }
}

extern "C" void kernel_launch(void* const* d_in, const int* in_sizes, int n_in,
                              void* d_out, int out_size, void* d_ws, size_t ws_size,
                              hipStream_t stream)
{
  const float* nf   = (const float*)d_in[0];
  const float* e    = (const float*)d_in[1];
  const float* dtt  = (const float*)d_in[2];
  const float* W_m  = (const float*)d_in[3];
  const float* U_m  = (const float*)d_in[4];
  const float* b_m  = (const float*)d_in[5];
  const float* Wd_m = (const float*)d_in[6];
  const float* bd_m = (const float*)d_in[7];
  const float* W_a  = (const float*)d_in[8];
  const float* U_a  = (const float*)d_in[9];
  const float* b_a  = (const float*)d_in[10];
  const float* Wd_a = (const float*)d_in[11];
  const float* bd_a = (const float*)d_in[12];
  const float* attn = (const float*)d_in[13];
  const float* eoW  = (const float*)d_in[14];
  const float* eob  = (const float*)d_in[15];
  const float* ndW  = (const float*)d_in[16];
  const float* ndb  = (const float*)d_in[17];
  const float* fcW  = (const float*)d_in[18];
  const float* fcb  = (const float*)d_in[19];
  const int* elen = (const int*)d_in[20];
  const int* srci = (const int*)d_in[21];

  char* ws = (char*)d_ws;
  u16* UWt_m  = (u16*)(ws + 0);
  u16* UWt_a  = (u16*)(ws + 163840);
  u16* WdT_m  = (u16*)(ws + 327680);
  u16* WdT_a  = (u16*)(ws + 360448);
  u16* eoWt   = (u16*)(ws + 393216);          // ends 458752
  u16* e_out  = (u16*)(ws + 458752);          // 16 MB
  float* aval = (float*)(ws + 17235968);      // 256 KB
  int* perm   = (int*)(ws + 17498112);        // 256 KB
  int* cnt    = (int*)(ws + 17760256);
  int* coff   = (int*)(ws + 17760320);
  u16* ndWt   = (u16*)(ws + 17760384);        // 64 KB
  u16* fcWt   = (u16*)(ws + 17825920);        // 4 KB
  float* sft  = (float*)(ws + 17830016);      // 1 MB
  u16* haggb  = (u16*)(ws + 18878592);        // 512 KB

  hipMemsetAsync(cnt, 0, 64, stream);
  prep_kernel<<<1032, 256, 0, stream>>>(U_m, W_m, U_a, W_a, Wd_m, Wd_a, eoW, ndW, fcW,
                                        UWt_m, UWt_a, WdT_m, WdT_a, eoWt, ndWt, fcWt);
  hist_kernel<<<EDGES / 256, 256, 0, stream>>>(elen, cnt);
  scan_kernel<<<1, 1, 0, stream>>>(cnt, coff);
  scatter_kernel<<<EDGES / 256, 256, 0, stream>>>(elen, coff, perm);
  pre_gemm<<<NDST / 32, 256, 0, stream>>>(nf, eob, eoWt, sft);
  lstm_kernel<<<2048, 512, 0, stream>>>(e, dtt, b_m, bd_m, b_a, bd_a, attn,
                                        elen, perm, UWt_m, UWt_a, WdT_m, WdT_a,
                                        e_out, aval);
  node_mid<<<NDST, 256, 0, stream>>>(nf, e_out, aval, eob, srci, eoWt, sft, haggb);
  post_gemm<<<NDST / 32, 256, 0, stream>>>(nf, haggb, ndb, ndWt, fcb, fcWt,
                                           (float*)d_out);
}

// Round 19
// 437.799 us; speedup vs baseline: 1.2223x; 1.0676x over previous
//
#include <hip/hip_runtime.h>

// GTEA T-LSTM forward. Inputs f32, OUTPUT f32. MFMA bf16 compute.
// Pipeline:
//   prep:     f32 weights -> packed bf16, exp-prescale folded in (phase B uses
//             2^x via __builtin_amdgcn_exp2f; raw asm TRANS op raced, r16).
//   sort:     counting-sort by e_len, hierarchical (ballot + 16 atomics/block)
//   pre_gemm: sft[2048][128] f32 = nf[:2048] @ eoW[0:128] + eob
//   lstm:     2048 blocks x 512 (8 waves x 16 cols), 64 edges/block, longest-first;
//             step split into two 32-edge groups: A(G0) B(G0) A(G1) B(G1) barrier
//             -> the barrier seam is padded with independent work and peak
//             accumulator pressure halves. A/C double-buffered; weights in VGPRs.
//   node_mid: per node: edge GEMM (MFMA) + sparsemax + aggregate - sft -> hagg bf16
//   post_gemm: acts = relu([selfh|hagg] @ ndW + ndb); out = acts @ fcW + fcb
// ws ~= 19.4 MB

typedef unsigned short u16;
typedef unsigned int u32;
typedef unsigned long long u64;
typedef float f32x4 __attribute__((ext_vector_type(4)));
typedef short bf16x8 __attribute__((ext_vector_type(8)));

#define NDST 2048
#define EDGES 65536
#define NL2E  -1.4426950408889634f   // -log2(e)
#define NL2E2 -2.8853900817779268f   // -2*log2(e)

__device__ __forceinline__ float bf2f(u16 u) {
  union { u32 i; float f; } v; v.i = ((u32)u) << 16; return v.f;
}
__device__ __forceinline__ u16 f2bf(float f) {
  u32 x = __builtin_bit_cast(u32, f);
  u32 r = x + 0x7fffu + ((x >> 16) & 1u);
  return (u16)(r >> 16);
}
__device__ __forceinline__ u32 cvtpk2(float lo, float hi) {
  u32 r;
  asm("v_cvt_pk_bf16_f32 %0, %1, %2" : "=v"(r) : "v"(lo), "v"(hi));
  return r;
}
__device__ __forceinline__ u16 f2bf_h(float f) { return (u16)(cvtpk2(f, f) & 0xffffu); }
__device__ __forceinline__ bf16x8 ldb8(const u16* p) {
  return *reinterpret_cast<const bf16x8*>(p);
}
__device__ __forceinline__ f32x4 mfma16(bf16x8 a, bf16x8 b, f32x4 c) {
  return __builtin_amdgcn_mfma_f32_16x16x32_bf16(a, b, c, 0, 0, 0);
}
__device__ __forceinline__ float rcp_(float x) { return __builtin_amdgcn_rcpf(x); }
__device__ __forceinline__ float ex2(float x) { return __builtin_amdgcn_exp2f(x); }

// ---------------- weight prep: f32 -> packed bf16 (exp-prescaled) ----------------
__global__ __launch_bounds__(256) void prep_kernel(
    const float* __restrict__ U_m, const float* __restrict__ W_m,
    const float* __restrict__ U_a, const float* __restrict__ W_a,
    const float* __restrict__ Wd_m, const float* __restrict__ Wd_a,
    const float* __restrict__ eoW, const float* __restrict__ ndW,
    const float* __restrict__ fcW,
    u16* __restrict__ UWt_m, u16* __restrict__ UWt_a,
    u16* __restrict__ WdT_m, u16* __restrict__ WdT_a, u16* __restrict__ eoWt,
    u16* __restrict__ ndWt, u16* __restrict__ fcWt)
{
  int idx = blockIdx.x * 256 + threadIdx.x;
  if (idx < 163840) {                          // UWt: [512 cols][160 k], prescaled
    int s = idx >= 81920 ? 1 : 0;
    int i = idx - s * 81920;
    int j = i / 160, k = i % 160;
    const float* U = s ? U_a : U_m;
    const float* W = s ? W_a : W_m;
    float v = 0.f;
    if (k < 128) v = U[k * 512 + j];
    else if (k < 144) v = W[(k - 128) * 512 + j];
    v *= (j < 384) ? NL2E : NL2E2;             // i,f,o: -log2e ; g: -2log2e
    (s ? UWt_a : UWt_m)[j * 160 + k] = f2bf(v);
  } else if (idx < 196608) {                   // WdT: [128 cols][128 k], x -2log2e
    int i = idx - 163840;
    int s = i >= 16384 ? 1 : 0;
    i -= s * 16384;
    int j = i >> 7, k = i & 127;
    (s ? WdT_a : WdT_m)[j * 128 + k] = f2bf((s ? Wd_a : Wd_m)[k * 128 + j] * NL2E2);
  } else if (idx < 229376) {                   // eoWt: [128 cols][256 k]
    int i = idx - 196608;
    int j = i >> 8, k = i & 255;
    eoWt[j * 256 + k] = f2bf(eoW[k * 128 + j]);
  } else if (idx < 262144) {                   // ndWt: [128 cols][256 k]
    int i = idx - 229376;
    int j = i >> 8, k = i & 255;
    ndWt[j * 256 + k] = f2bf(ndW[k * 128 + j]);
  } else if (idx < 264192) {                   // fcWt: [16 cols][128 k]
    int i = idx - 262144;
    int j = i >> 7, k = i & 127;
    fcWt[j * 128 + k] = (j < 10) ? f2bf(fcW[k * 10 + j]) : (u16)0;
  }
}

// ---------------- counting sort by e_len (hierarchical) ----------------
__global__ __launch_bounds__(256) void hist_kernel(const int* __restrict__ elen,
                                                   int* __restrict__ cnt) {
  __shared__ int wcnt[4][16];
  const int tid = threadIdx.x;
  const int e = blockIdx.x * 256 + tid;
  const int wv = tid >> 6, ln = tid & 63;
  const int b = min(max(elen[e] - 1, 0), 15);
#pragma unroll
  for (int bb = 0; bb < 16; ++bb) {
    u64 m = __ballot(b == bb);
    if (ln == 0) wcnt[wv][bb] = __popcll(m);
  }
  __syncthreads();
  if (tid < 16)
    atomicAdd(&cnt[tid], wcnt[0][tid] + wcnt[1][tid] + wcnt[2][tid] + wcnt[3][tid]);
}
__global__ void scan_kernel(const int* __restrict__ cnt, int* __restrict__ coff) {
  if (threadIdx.x == 0 && blockIdx.x == 0) {
    int a = 0;
    for (int i = 0; i < 16; ++i) { coff[i] = a; a += cnt[i]; }
  }
}
__global__ __launch_bounds__(256) void scatter_kernel(const int* __restrict__ elen,
                                                      int* __restrict__ coff,
                                                      int* __restrict__ perm) {
  __shared__ int wcnt[4][16];
  __shared__ int base[16];
  const int tid = threadIdx.x;
  const int e = blockIdx.x * 256 + tid;
  const int wv = tid >> 6, ln = tid & 63;
  const int b = min(max(elen[e] - 1, 0), 15);
  int intrarank = 0;
#pragma unroll
  for (int bb = 0; bb < 16; ++bb) {
    u64 m = __ballot(b == bb);
    if (bb == b) intrarank = __popcll(m & ((1ull << ln) - 1ull));
    if (ln == 0) wcnt[wv][bb] = __popcll(m);
  }
  __syncthreads();
  if (tid < 16) {
    int s = wcnt[0][tid] + wcnt[1][tid] + wcnt[2][tid] + wcnt[3][tid];
    base[tid] = atomicAdd(&coff[tid], s);
  }
  __syncthreads();
  int prior = 0;
  for (int w = 0; w < wv; ++w) prior += wcnt[w][b];
  perm[base[b] + prior + intrarank] = e;
}

// ---------------- pre: sft = nf[:2048] @ eoW[0:128] + eob ----------------
__global__ __launch_bounds__(256) void pre_gemm(
    const float* __restrict__ nf, const float* __restrict__ eob,
    const u16* __restrict__ eoWt, float* __restrict__ sft)
{
  const int n0 = blockIdx.x * 32;
  const int tid = threadIdx.x;
  const int w = tid >> 6, lane = tid & 63, l15 = lane & 15, lhi = lane >> 4;
  __shared__ __align__(16) u16 A3[32 * 136];

  {
    const int row = tid >> 3, p = tid & 7;
    const float4* ph = reinterpret_cast<const float4*>(nf + (size_t)(n0 + row) * 128 + p * 16);
    float4 f0 = ph[0], f1 = ph[1], f2 = ph[2], f3 = ph[3];
    uint4 pk0, pk1;
    pk0.x = cvtpk2(f0.x, f0.y); pk0.y = cvtpk2(f0.z, f0.w);
    pk0.z = cvtpk2(f1.x, f1.y); pk0.w = cvtpk2(f1.z, f1.w);
    pk1.x = cvtpk2(f2.x, f2.y); pk1.y = cvtpk2(f2.z, f2.w);
    pk1.z = cvtpk2(f3.x, f3.y); pk1.w = cvtpk2(f3.z, f3.w);
    *reinterpret_cast<uint4*>(&A3[row * 136 + p * 16]) = pk0;
    *reinterpret_cast<uint4*>(&A3[row * 136 + p * 16 + 8]) = pk1;
  }
  __syncthreads();
  f32x4 acc[2][2];
  const int j0 = w * 32 + l15, j1 = w * 32 + 16 + l15;
  {
    float v0 = eob[j0], v1 = eob[j1];
    f32x4 t0 = {v0, v0, v0, v0}, t1 = {v1, v1, v1, v1};
    acc[0][0] = t0; acc[1][0] = t0;
    acc[0][1] = t1; acc[1][1] = t1;
  }
#pragma unroll
  for (int ks = 0; ks < 4; ++ks) {
    bf16x8 a0 = ldb8(&A3[l15 * 136 + ks * 32 + lhi * 8]);
    bf16x8 a1 = ldb8(&A3[(16 + l15) * 136 + ks * 32 + lhi * 8]);
    bf16x8 b0 = ldb8(eoWt + (size_t)j0 * 256 + ks * 32 + lhi * 8);
    bf16x8 b1 = ldb8(eoWt + (size_t)j1 * 256 + ks * 32 + lhi * 8);
    acc[0][0] = mfma16(a0, b0, acc[0][0]);
    acc[1][0] = mfma16(a1, b0, acc[1][0]);
    acc[0][1] = mfma16(a0, b1, acc[0][1]);
    acc[1][1] = mfma16(a1, b1, acc[1][1]);
  }
#pragma unroll
  for (int m = 0; m < 2; ++m)
#pragma unroll
    for (int n = 0; n < 2; ++n)
#pragma unroll
      for (int r = 0; r < 4; ++r) {
        const int row = m * 16 + lhi * 4 + r;
        const int j = w * 32 + n * 16 + l15;
        sft[(size_t)(n0 + row) * 128 + j] = acc[m][n][r];
      }
}

// ---------------- T-LSTM: 8 waves x 16 cols, 64 edges/block, 2-group interleave ----------------
__global__ __launch_bounds__(512, 2)
void lstm_kernel(
    const float* __restrict__ e, const float* __restrict__ dtt,
    const float* __restrict__ b_m, const float* __restrict__ bd_m,
    const float* __restrict__ b_a, const float* __restrict__ bd_a,
    const float* __restrict__ attn,
    const int* __restrict__ elen, const int* __restrict__ perm,
    const u16* __restrict__ UWt_m, const u16* __restrict__ UWt_a,
    const u16* __restrict__ WdT_m, const u16* __restrict__ WdT_a,
    u16* __restrict__ e_out, float* __restrict__ aval_g)
{
  const int bid = blockIdx.x;
  const int sel = bid >> 10;             // 0 = message LSTM, 1 = attention LSTM
  const int edge0 = (1023 - (bid & 1023)) * 64;   // longest-first (LPT)
  const u16* UWt = sel ? UWt_a : UWt_m;
  const u16* WdT = sel ? WdT_a : WdT_m;
  const float* bg  = sel ? b_a  : b_m;
  const float* bdp = sel ? bd_a : bd_m;

  __shared__ __align__(16) u16 Abuf[2][64 * 168];
  __shared__ __align__(16) u16 Cbuf[2][64 * 136];
  __shared__ __align__(16) u16 Eo[64 * 136];
  __shared__ float dec_all[16][64];
  __shared__ int rowedge[64], elen_s[64], tmax_s;

  const int tid = threadIdx.x;
  const int ww = tid >> 6, lane = tid & 63, l15 = lane & 15, lhi = lane >> 4;
  const int j = ww * 16 + l15;
  const int srow = tid >> 3, sp = tid & 7;

  if (tid < 64) {
    int ed = perm[edge0 + tid];
    rowedge[tid] = ed;
    elen_s[tid] = min(max(elen[ed], 1), 16);
  }
  for (int i = tid; i < 2 * 64 * 168; i += 512) (&Abuf[0][0])[i] = 0;
  for (int i = tid; i < 2 * 64 * 136; i += 512) (&Cbuf[0][0])[i] = 0;
  __syncthreads();
  if (tid == 0) {
    int mx = 1;
    for (int i = 0; i < 64; ++i) mx = max(mx, elen_s[i]);
    tmax_s = mx;
  }
  for (int i = tid; i < 1024; i += 512) {
    int row = i & 63, t = i >> 6;
    dec_all[t][row] =
        1.f / logf(2.7182818284590452f + dtt[(size_t)rowedge[row] * 16 + t]);
  }
  {
    float2 e2 = *reinterpret_cast<const float2*>(e + (size_t)rowedge[srow] * 256 + sp * 2);
    *reinterpret_cast<u32*>(&Abuf[0][srow * 168 + 128 + sp * 2]) = cvtpk2(e2.x, e2.y);
  }

  // ---- persistent weight fragments (prescaled): 24 frags = 96 VGPRs/wave ----
  bf16x8 BU[5][4];
#pragma unroll
  for (int ks = 0; ks < 5; ++ks)
#pragma unroll
    for (int g = 0; g < 4; ++g)
      BU[ks][g] = ldb8(UWt + (size_t)(g * 128 + j) * 160 + ks * 32 + lhi * 8);
  bf16x8 BD[4];
#pragma unroll
  for (int ks = 0; ks < 4; ++ks)
    BD[ks] = ldb8(WdT + (size_t)j * 128 + ks * 32 + lhi * 8);
#pragma unroll
  for (int ks = 0; ks < 5; ++ks)
#pragma unroll
    for (int g = 0; g < 4; ++g)
      asm volatile("" : "+v"(BU[ks][g]));
#pragma unroll
  for (int ks = 0; ks < 4; ++ks)
    asm volatile("" : "+v"(BD[ks]));

  f32x4 bias4[4];
#pragma unroll
  for (int g = 0; g < 4; ++g) {
    float b = bg[g * 128 + j] * ((g < 3) ? NL2E : NL2E2);
    f32x4 t = {b, b, b, b};
    bias4[g] = t;
  }
  f32x4 bds4;
  {
    float b = bdp[j] * NL2E2;
    f32x4 t = {b, b, b, b};
    bds4 = t;
  }

  float cst[4][4];
#pragma unroll
  for (int mt = 0; mt < 4; ++mt)
#pragma unroll
    for (int r = 0; r < 4; ++r) cst[mt][r] = 0.f;
  __syncthreads();
  const int tmax = tmax_s;

  for (int t = 0; t < tmax; ++t) {
    const u16* Ar = Abuf[t & 1];
    const u16* Cr = Cbuf[t & 1];
    u16* Aw = Abuf[(t + 1) & 1];
    u16* Cw = Cbuf[(t + 1) & 1];

    // T14 split: issue next e_t load early; LDS-write after both groups' phase B
    float2 e2n;
    const bool stage_next = (t + 1 < tmax);
    if (stage_next)
      e2n = *reinterpret_cast<const float2*>(
          e + (size_t)rowedge[srow] * 256 + (t + 1) * 16 + sp * 2);

    // ---- two 32-edge groups: A(G) then B(G); barrier only at step end.
    // B(G0) writes Aw rows 0-31, A(G1) reads Ar rows 32-63 -> disjoint, safe.
#pragma unroll
    for (int grp = 0; grp < 2; ++grp) {
      const int mt0 = grp * 2;
      f32x4 acc[2][4];
      f32x4 accs[2];
#pragma unroll
      for (int mh = 0; mh < 2; ++mh) {
        bf16x8 a = ldb8(&Ar[((mt0 + mh) * 16 + l15) * 168 + lhi * 8]);
#pragma unroll
        for (int g = 0; g < 4; ++g)
          acc[mh][g] = mfma16(a, BU[0][g], bias4[g]);
      }
#pragma unroll
      for (int ks = 1; ks < 5; ++ks) {
#pragma unroll
        for (int mh = 0; mh < 2; ++mh) {
          bf16x8 a = ldb8(&Ar[((mt0 + mh) * 16 + l15) * 168 + ks * 32 + lhi * 8]);
#pragma unroll
          for (int g = 0; g < 4; ++g)
            acc[mh][g] = mfma16(a, BU[ks][g], acc[mh][g]);
        }
      }
#pragma unroll
      for (int mh = 0; mh < 2; ++mh) {
        bf16x8 c = ldb8(&Cr[((mt0 + mh) * 16 + l15) * 136 + lhi * 8]);
        accs[mh] = mfma16(c, BD[0], bds4);
      }
#pragma unroll
      for (int ks = 1; ks < 4; ++ks) {
#pragma unroll
        for (int mh = 0; mh < 2; ++mh) {
          bf16x8 c = ldb8(&Cr[((mt0 + mh) * 16 + l15) * 136 + ks * 32 + lhi * 8]);
          accs[mh] = mfma16(c, BD[ks], accs[mh]);
        }
      }
      // phase B for this group
#pragma unroll
      for (int mh = 0; mh < 2; ++mh)
#pragma unroll
        for (int r = 0; r < 4; ++r) {
          const int mt = mt0 + mh;
          const int row = mt * 16 + lhi * 4 + r;
          float iv = rcp_(1.f + ex2(acc[mh][0][r]));
          float fv = rcp_(1.f + ex2(acc[mh][1][r]));
          float ov = rcp_(1.f + ex2(acc[mh][2][r]));
          float gv = 2.f * rcp_(1.f + ex2(acc[mh][3][r])) - 1.f;
          float cs = 2.f * rcp_(1.f + ex2(accs[mh][r])) - 1.f;
          float dec = dec_all[t][row];
          float co = cst[mt][r];
          float cstar = co + cs * (dec - 1.f);   // c - c_s + c_s*dec
          float cn = fv * cstar + iv * gv;
          float th = 2.f * rcp_(1.f + ex2(cn * NL2E2)) - 1.f;
          float hn = ov * th;
          cst[mt][r] = cn;
          u16 hb = f2bf_h(hn);
          Aw[row * 168 + j] = hb;
          Cw[row * 136 + j] = f2bf_h(cn);
          if (elen_s[row] == t + 1) Eo[row * 136 + j] = hb;
        }
    }
    if (stage_next)
      *reinterpret_cast<u32*>(&Aw[srow * 168 + 128 + sp * 2]) = cvtpk2(e2n.x, e2n.y);
    __syncthreads();   // single barrier per step
  }

  if (sel) {   // attention logit
    if (tid < 64) {
      float s = 0.f;
      for (int k = 0; k < 128; ++k) s += bf2f(Eo[tid * 136 + k]) * attn[k];
      aval_g[rowedge[tid]] = s > 0.f ? s : 0.01f * s;
    }
  } else {     // e_out writeback
    uint4 v0 = *reinterpret_cast<const uint4*>(&Eo[srow * 136 + sp * 16]);
    uint4 v1 = *reinterpret_cast<const uint4*>(&Eo[srow * 136 + sp * 16 + 8]);
    u16* dst = e_out + (size_t)rowedge[srow] * 128 + sp * 16;
    *reinterpret_cast<uint4*>(dst) = v0;
    *reinterpret_cast<uint4*>(dst + 8) = v1;
  }
}

// ---------------- node mid: edge GEMM + sparsemax + aggregate -> hagg bf16 ----------------
__global__ __launch_bounds__(256) void node_mid(
    const float* __restrict__ nf, const u16* __restrict__ e_out,
    const float* __restrict__ aval_g, const float* __restrict__ eob,
    const int* __restrict__ srci, const u16* __restrict__ eoWt,
    const float* __restrict__ sft, u16* __restrict__ haggb)
{
  const int node = blockIdx.x;
  const int tid = threadIdx.x;
  const int ebase = node * 32;
  const int w = tid >> 6, lane = tid & 63, l15 = lane & 15, lhi = lane >> 4;

  __shared__ __align__(16) u16 A2[32 * 264];
  __shared__ __align__(16) u16 Msh[32 * 136];
  __shared__ float aval[32], zsrc[32], zs[32], redf[32], alpha_s[32];
  __shared__ int redi[32];

  {
    const int row = tid >> 3, p = tid & 7;
    const int src = srci[ebase + row];
    const float4* ph = reinterpret_cast<const float4*>(nf + (size_t)src * 128 + p * 16);
    float4 f0 = ph[0], f1 = ph[1], f2 = ph[2], f3 = ph[3];
    uint4 pk0, pk1;
    pk0.x = cvtpk2(f0.x, f0.y); pk0.y = cvtpk2(f0.z, f0.w);
    pk0.z = cvtpk2(f1.x, f1.y); pk0.w = cvtpk2(f1.z, f1.w);
    pk1.x = cvtpk2(f2.x, f2.y); pk1.y = cvtpk2(f2.z, f2.w);
    pk1.z = cvtpk2(f3.x, f3.y); pk1.w = cvtpk2(f3.z, f3.w);
    *reinterpret_cast<uint4*>(&A2[row * 264 + p * 16]) = pk0;
    *reinterpret_cast<uint4*>(&A2[row * 264 + p * 16 + 8]) = pk1;
    const u16* pe = e_out + (size_t)(ebase + row) * 128 + p * 16;
    *reinterpret_cast<uint4*>(&A2[row * 264 + 128 + p * 16]) =
        *reinterpret_cast<const uint4*>(pe);
    *reinterpret_cast<uint4*>(&A2[row * 264 + 128 + p * 16 + 8]) =
        *reinterpret_cast<const uint4*>(pe + 8);
  }
  if (tid < 32) aval[tid] = aval_g[ebase + tid];
  __syncthreads();

  {
    f32x4 eacc[2][2];
    const int j0 = w * 32 + l15, j1 = w * 32 + 16 + l15;
    {
      float v0 = eob[j0], v1 = eob[j1];
      f32x4 t0 = {v0, v0, v0, v0}, t1 = {v1, v1, v1, v1};
      eacc[0][0] = t0; eacc[1][0] = t0;
      eacc[0][1] = t1; eacc[1][1] = t1;
    }
#pragma unroll
    for (int ks = 0; ks < 8; ++ks) {
      bf16x8 a0 = ldb8(&A2[l15 * 264 + ks * 32 + lhi * 8]);
      bf16x8 a1 = ldb8(&A2[(16 + l15) * 264 + ks * 32 + lhi * 8]);
      bf16x8 b0 = ldb8(eoWt + (size_t)j0 * 256 + ks * 32 + lhi * 8);
      bf16x8 b1 = ldb8(eoWt + (size_t)j1 * 256 + ks * 32 + lhi * 8);
      eacc[0][0] = mfma16(a0, b0, eacc[0][0]);
      eacc[1][0] = mfma16(a1, b0, eacc[1][0]);
      eacc[0][1] = mfma16(a0, b1, eacc[0][1]);
      eacc[1][1] = mfma16(a1, b1, eacc[1][1]);
    }
#pragma unroll
    for (int m = 0; m < 2; ++m)
#pragma unroll
      for (int n = 0; n < 2; ++n)
#pragma unroll
        for (int r = 0; r < 4; ++r) {
          const int row = m * 16 + lhi * 4 + r;
          const int jj = w * 32 + n * 16 + l15;
          Msh[row * 136 + jj] = f2bf_h(fmaxf(eacc[m][n][r], 0.f));
        }
  }
  __syncthreads();

  if (tid < 32) {
    float mx = -1e30f;
    for (int jj = 0; jj < 32; ++jj) mx = fmaxf(mx, aval[jj]);
    float z = aval[tid] - mx;
    zsrc[tid] = z;
    int rank = 0;
    for (int jj = 0; jj < 32; ++jj) {
      float zj = aval[jj] - mx;
      rank += (zj > z) || (zj == z && jj < tid);
    }
    zs[rank] = z;
  }
  __syncthreads();
  if (tid < 32) {
    float cum = 0.f;
    for (int s = 0; s <= tid; ++s) cum += zs[s];
    float zst = zs[tid];
    bool isg = (1.f + (float)(tid + 1) * zst) > cum;
    redf[tid] = isg ? zst : 0.f;
    redi[tid] = isg ? (tid + 1) : 0;
  }
  __syncthreads();
  if (tid < 32) {
    int kk = 0; float ss = 0.f;
    for (int jj = 0; jj < 32; ++jj) { kk = max(kk, redi[jj]); ss += redf[jj]; }
    float tau = (ss - 1.f) / (float)kk;
    alpha_s[tid] = fmaxf(0.f, zsrc[tid] - tau);
  }
  __syncthreads();

  if (tid < 128) {
    float s = 0.f;
    for (int d = 0; d < 32; ++d) s += alpha_s[d] * bf2f(Msh[d * 136 + tid]);
    haggb[(size_t)node * 128 + tid] = f2bf_h(s - sft[(size_t)node * 128 + tid]);
  }
}

// ---------------- post: acts = relu([selfh|hagg]@ndW + ndb); out = acts@fcW + fcb ----------------
__global__ __launch_bounds__(256) void post_gemm(
    const float* __restrict__ nf, const u16* __restrict__ haggb,
    const float* __restrict__ ndb, const u16* __restrict__ ndWt,
    const float* __restrict__ fcb, const u16* __restrict__ fcWt,
    float* __restrict__ out)
{
  const int n0 = blockIdx.x * 32;
  const int tid = threadIdx.x;
  const int w = tid >> 6, lane = tid & 63, l15 = lane & 15, lhi = lane >> 4;
  __shared__ __align__(16) u16 A3[32 * 264];
  __shared__ __align__(16) u16 Acts[32 * 136];

  {
    const int row = tid >> 3, p = tid & 7;
    const float4* ph = reinterpret_cast<const float4*>(nf + (size_t)(n0 + row) * 128 + p * 16);
    float4 f0 = ph[0], f1 = ph[1], f2 = ph[2], f3 = ph[3];
    uint4 pk0, pk1;
    pk0.x = cvtpk2(f0.x, f0.y); pk0.y = cvtpk2(f0.z, f0.w);
    pk0.z = cvtpk2(f1.x, f1.y); pk0.w = cvtpk2(f1.z, f1.w);
    pk1.x = cvtpk2(f2.x, f2.y); pk1.y = cvtpk2(f2.z, f2.w);
    pk1.z = cvtpk2(f3.x, f3.y); pk1.w = cvtpk2(f3.z, f3.w);
    *reinterpret_cast<uint4*>(&A3[row * 264 + p * 16]) = pk0;
    *reinterpret_cast<uint4*>(&A3[row * 264 + p * 16 + 8]) = pk1;
    const u16* pg = haggb + (size_t)(n0 + row) * 128 + p * 16;
    *reinterpret_cast<uint4*>(&A3[row * 264 + 128 + p * 16]) =
        *reinterpret_cast<const uint4*>(pg);
    *reinterpret_cast<uint4*>(&A3[row * 264 + 128 + p * 16 + 8]) =
        *reinterpret_cast<const uint4*>(pg + 8);
  }
  __syncthreads();

  {
    f32x4 acc[2][2];
    const int j0 = w * 32 + l15, j1 = w * 32 + 16 + l15;
    {
      float v0 = ndb[j0], v1 = ndb[j1];
      f32x4 t0 = {v0, v0, v0, v0}, t1 = {v1, v1, v1, v1};
      acc[0][0] = t0; acc[1][0] = t0;
      acc[0][1] = t1; acc[1][1] = t1;
    }
#pragma unroll
    for (int ks = 0; ks < 8; ++ks) {
      bf16x8 a0 = ldb8(&A3[l15 * 264 + ks * 32 + lhi * 8]);
      bf16x8 a1 = ldb8(&A3[(16 + l15) * 264 + ks * 32 + lhi * 8]);
      bf16x8 b0 = ldb8(ndWt + (size_t)j0 * 256 + ks * 32 + lhi * 8);
      bf16x8 b1 = ldb8(ndWt + (size_t)j1 * 256 + ks * 32 + lhi * 8);
      acc[0][0] = mfma16(a0, b0, acc[0][0]);
      acc[1][0] = mfma16(a1, b0, acc[1][0]);
      acc[0][1] = mfma16(a0, b1, acc[0][1]);
      acc[1][1] = mfma16(a1, b1, acc[1][1]);
    }
#pragma unroll
    for (int m = 0; m < 2; ++m)
#pragma unroll
      for (int n = 0; n < 2; ++n)
#pragma unroll
        for (int r = 0; r < 4; ++r) {
          const int row = m * 16 + lhi * 4 + r;
          const int jj = w * 32 + n * 16 + l15;
          Acts[row * 136 + jj] = f2bf_h(fmaxf(acc[m][n][r], 0.f));
        }
  }
  __syncthreads();

  if (w < 2) {
    const int m = w;
    f32x4 acc1;
    {
      float v = (l15 < 10) ? fcb[l15] : 0.f;
      f32x4 t = {v, v, v, v};
      acc1 = t;
    }
#pragma unroll
    for (int ks = 0; ks < 4; ++ks) {
      bf16x8 a = ldb8(&Acts[(m * 16 + l15) * 136 + ks * 32 + lhi * 8]);
      bf16x8 b = ldb8(fcWt + (size_t)l15 * 128 + ks * 32 + lhi * 8);
      acc1 = mfma16(a, b, acc1);
    }
    if (l15 < 10) {
#pragma unroll
      for (int r = 0; r < 4; ++r) {
        const int row = m * 16 + lhi * 4 + r;
        out[(size_t)(n0 + row) * 10 + l15] = acc1[r];
      }
    }
  }
}

extern "C" void kernel_launch(void* const* d_in, const int* in_sizes, int n_in,
                              void* d_out, int out_size, void* d_ws, size_t ws_size,
                              hipStream_t stream)
{
  const float* nf   = (const float*)d_in[0];
  const float* e    = (const float*)d_in[1];
  const float* dtt  = (const float*)d_in[2];
  const float* W_m  = (const float*)d_in[3];
  const float* U_m  = (const float*)d_in[4];
  const float* b_m  = (const float*)d_in[5];
  const float* Wd_m = (const float*)d_in[6];
  const float* bd_m = (const float*)d_in[7];
  const float* W_a  = (const float*)d_in[8];
  const float* U_a  = (const float*)d_in[9];
  const float* b_a  = (const float*)d_in[10];
  const float* Wd_a = (const float*)d_in[11];
  const float* bd_a = (const float*)d_in[12];
  const float* attn = (const float*)d_in[13];
  const float* eoW  = (const float*)d_in[14];
  const float* eob  = (const float*)d_in[15];
  const float* ndW  = (const float*)d_in[16];
  const float* ndb  = (const float*)d_in[17];
  const float* fcW  = (const float*)d_in[18];
  const float* fcb  = (const float*)d_in[19];
  const int* elen = (const int*)d_in[20];
  const int* srci = (const int*)d_in[21];

  char* ws = (char*)d_ws;
  u16* UWt_m  = (u16*)(ws + 0);
  u16* UWt_a  = (u16*)(ws + 163840);
  u16* WdT_m  = (u16*)(ws + 327680);
  u16* WdT_a  = (u16*)(ws + 360448);
  u16* eoWt   = (u16*)(ws + 393216);          // ends 458752
  u16* e_out  = (u16*)(ws + 458752);          // 16 MB
  float* aval = (float*)(ws + 17235968);      // 256 KB
  int* perm   = (int*)(ws + 17498112);        // 256 KB
  int* cnt    = (int*)(ws + 17760256);
  int* coff   = (int*)(ws + 17760320);
  u16* ndWt   = (u16*)(ws + 17760384);        // 64 KB
  u16* fcWt   = (u16*)(ws + 17825920);        // 4 KB
  float* sft  = (float*)(ws + 17830016);      // 1 MB
  u16* haggb  = (u16*)(ws + 18878592);        // 512 KB

  hipMemsetAsync(cnt, 0, 64, stream);
  prep_kernel<<<1032, 256, 0, stream>>>(U_m, W_m, U_a, W_a, Wd_m, Wd_a, eoW, ndW, fcW,
                                        UWt_m, UWt_a, WdT_m, WdT_a, eoWt, ndWt, fcWt);
  hist_kernel<<<EDGES / 256, 256, 0, stream>>>(elen, cnt);
  scan_kernel<<<1, 1, 0, stream>>>(cnt, coff);
  scatter_kernel<<<EDGES / 256, 256, 0, stream>>>(elen, coff, perm);
  pre_gemm<<<NDST / 32, 256, 0, stream>>>(nf, eob, eoWt, sft);
  lstm_kernel<<<2048, 512, 0, stream>>>(e, dtt, b_m, bd_m, b_a, bd_a, attn,
                                        elen, perm, UWt_m, UWt_a, WdT_m, WdT_a,
                                        e_out, aval);
  node_mid<<<NDST, 256, 0, stream>>>(nf, e_out, aval, eob, srci, eoWt, sft, haggb);
  post_gemm<<<NDST / 32, 256, 0, stream>>>(nf, haggb, ndb, ndWt, fcb, fcWt,
                                           (float*)d_out);
}

// Round 20
// 432.655 us; speedup vs baseline: 1.2369x; 1.0119x over previous
//
#include <hip/hip_runtime.h>

// GTEA T-LSTM forward. Inputs f32, OUTPUT f32. MFMA bf16 compute.
// Pipeline:
//   prep:     f32 weights -> packed bf16, exp-prescale folded in (phase B uses
//             2^x via __builtin_amdgcn_exp2f; raw asm TRANS op raced, r16).
//   sort:     counting-sort by e_len, hierarchical (ballot + 16 atomics/block)
//   pre_gemm: sft[2048][128] f32 = nf[:2048] @ eoW[0:128] + eob
//   lstm:     2048 blocks x 512 (8 waves x 16 cols), 64 edges/block, longest-first;
//             step split into FOUR 16-edge groups A(G)B(G) x4 then barrier
//             -> 3 internal seams for software pipelining, 1/4 acc pressure.
//             A/C double-buffered; weights persistent in VGPRs.
//   node_mid: per node: edge GEMM (MFMA) + sparsemax + aggregate - sft -> hagg bf16
//   post_gemm: acts = relu([selfh|hagg] @ ndW + ndb); out = acts @ fcW + fcb
// ws ~= 19.4 MB

typedef unsigned short u16;
typedef unsigned int u32;
typedef unsigned long long u64;
typedef float f32x4 __attribute__((ext_vector_type(4)));
typedef short bf16x8 __attribute__((ext_vector_type(8)));

#define NDST 2048
#define EDGES 65536
#define NL2E  -1.4426950408889634f   // -log2(e)
#define NL2E2 -2.8853900817779268f   // -2*log2(e)

__device__ __forceinline__ float bf2f(u16 u) {
  union { u32 i; float f; } v; v.i = ((u32)u) << 16; return v.f;
}
__device__ __forceinline__ u16 f2bf(float f) {
  u32 x = __builtin_bit_cast(u32, f);
  u32 r = x + 0x7fffu + ((x >> 16) & 1u);
  return (u16)(r >> 16);
}
__device__ __forceinline__ u32 cvtpk2(float lo, float hi) {
  u32 r;
  asm("v_cvt_pk_bf16_f32 %0, %1, %2" : "=v"(r) : "v"(lo), "v"(hi));
  return r;
}
__device__ __forceinline__ u16 f2bf_h(float f) { return (u16)(cvtpk2(f, f) & 0xffffu); }
__device__ __forceinline__ bf16x8 ldb8(const u16* p) {
  return *reinterpret_cast<const bf16x8*>(p);
}
__device__ __forceinline__ f32x4 mfma16(bf16x8 a, bf16x8 b, f32x4 c) {
  return __builtin_amdgcn_mfma_f32_16x16x32_bf16(a, b, c, 0, 0, 0);
}
__device__ __forceinline__ float rcp_(float x) { return __builtin_amdgcn_rcpf(x); }
__device__ __forceinline__ float ex2(float x) { return __builtin_amdgcn_exp2f(x); }

// ---------------- weight prep: f32 -> packed bf16 (exp-prescaled) ----------------
__global__ __launch_bounds__(256) void prep_kernel(
    const float* __restrict__ U_m, const float* __restrict__ W_m,
    const float* __restrict__ U_a, const float* __restrict__ W_a,
    const float* __restrict__ Wd_m, const float* __restrict__ Wd_a,
    const float* __restrict__ eoW, const float* __restrict__ ndW,
    const float* __restrict__ fcW,
    u16* __restrict__ UWt_m, u16* __restrict__ UWt_a,
    u16* __restrict__ WdT_m, u16* __restrict__ WdT_a, u16* __restrict__ eoWt,
    u16* __restrict__ ndWt, u16* __restrict__ fcWt)
{
  int idx = blockIdx.x * 256 + threadIdx.x;
  if (idx < 163840) {                          // UWt: [512 cols][160 k], prescaled
    int s = idx >= 81920 ? 1 : 0;
    int i = idx - s * 81920;
    int j = i / 160, k = i % 160;
    const float* U = s ? U_a : U_m;
    const float* W = s ? W_a : W_m;
    float v = 0.f;
    if (k < 128) v = U[k * 512 + j];
    else if (k < 144) v = W[(k - 128) * 512 + j];
    v *= (j < 384) ? NL2E : NL2E2;             // i,f,o: -log2e ; g: -2log2e
    (s ? UWt_a : UWt_m)[j * 160 + k] = f2bf(v);
  } else if (idx < 196608) {                   // WdT: [128 cols][128 k], x -2log2e
    int i = idx - 163840;
    int s = i >= 16384 ? 1 : 0;
    i -= s * 16384;
    int j = i >> 7, k = i & 127;
    (s ? WdT_a : WdT_m)[j * 128 + k] = f2bf((s ? Wd_a : Wd_m)[k * 128 + j] * NL2E2);
  } else if (idx < 229376) {                   // eoWt: [128 cols][256 k]
    int i = idx - 196608;
    int j = i >> 8, k = i & 255;
    eoWt[j * 256 + k] = f2bf(eoW[k * 128 + j]);
  } else if (idx < 262144) {                   // ndWt: [128 cols][256 k]
    int i = idx - 229376;
    int j = i >> 8, k = i & 255;
    ndWt[j * 256 + k] = f2bf(ndW[k * 128 + j]);
  } else if (idx < 264192) {                   // fcWt: [16 cols][128 k]
    int i = idx - 262144;
    int j = i >> 7, k = i & 127;
    fcWt[j * 128 + k] = (j < 10) ? f2bf(fcW[k * 10 + j]) : (u16)0;
  }
}

// ---------------- counting sort by e_len (hierarchical) ----------------
__global__ __launch_bounds__(256) void hist_kernel(const int* __restrict__ elen,
                                                   int* __restrict__ cnt) {
  __shared__ int wcnt[4][16];
  const int tid = threadIdx.x;
  const int e = blockIdx.x * 256 + tid;
  const int wv = tid >> 6, ln = tid & 63;
  const int b = min(max(elen[e] - 1, 0), 15);
#pragma unroll
  for (int bb = 0; bb < 16; ++bb) {
    u64 m = __ballot(b == bb);
    if (ln == 0) wcnt[wv][bb] = __popcll(m);
  }
  __syncthreads();
  if (tid < 16)
    atomicAdd(&cnt[tid], wcnt[0][tid] + wcnt[1][tid] + wcnt[2][tid] + wcnt[3][tid]);
}
__global__ void scan_kernel(const int* __restrict__ cnt, int* __restrict__ coff) {
  if (threadIdx.x == 0 && blockIdx.x == 0) {
    int a = 0;
    for (int i = 0; i < 16; ++i) { coff[i] = a; a += cnt[i]; }
  }
}
__global__ __launch_bounds__(256) void scatter_kernel(const int* __restrict__ elen,
                                                      int* __restrict__ coff,
                                                      int* __restrict__ perm) {
  __shared__ int wcnt[4][16];
  __shared__ int base[16];
  const int tid = threadIdx.x;
  const int e = blockIdx.x * 256 + tid;
  const int wv = tid >> 6, ln = tid & 63;
  const int b = min(max(elen[e] - 1, 0), 15);
  int intrarank = 0;
#pragma unroll
  for (int bb = 0; bb < 16; ++bb) {
    u64 m = __ballot(b == bb);
    if (bb == b) intrarank = __popcll(m & ((1ull << ln) - 1ull));
    if (ln == 0) wcnt[wv][bb] = __popcll(m);
  }
  __syncthreads();
  if (tid < 16) {
    int s = wcnt[0][tid] + wcnt[1][tid] + wcnt[2][tid] + wcnt[3][tid];
    base[tid] = atomicAdd(&coff[tid], s);
  }
  __syncthreads();
  int prior = 0;
  for (int w = 0; w < wv; ++w) prior += wcnt[w][b];
  perm[base[b] + prior + intrarank] = e;
}

// ---------------- pre: sft = nf[:2048] @ eoW[0:128] + eob ----------------
__global__ __launch_bounds__(256) void pre_gemm(
    const float* __restrict__ nf, const float* __restrict__ eob,
    const u16* __restrict__ eoWt, float* __restrict__ sft)
{
  const int n0 = blockIdx.x * 32;
  const int tid = threadIdx.x;
  const int w = tid >> 6, lane = tid & 63, l15 = lane & 15, lhi = lane >> 4;
  __shared__ __align__(16) u16 A3[32 * 136];

  {
    const int row = tid >> 3, p = tid & 7;
    const float4* ph = reinterpret_cast<const float4*>(nf + (size_t)(n0 + row) * 128 + p * 16);
    float4 f0 = ph[0], f1 = ph[1], f2 = ph[2], f3 = ph[3];
    uint4 pk0, pk1;
    pk0.x = cvtpk2(f0.x, f0.y); pk0.y = cvtpk2(f0.z, f0.w);
    pk0.z = cvtpk2(f1.x, f1.y); pk0.w = cvtpk2(f1.z, f1.w);
    pk1.x = cvtpk2(f2.x, f2.y); pk1.y = cvtpk2(f2.z, f2.w);
    pk1.z = cvtpk2(f3.x, f3.y); pk1.w = cvtpk2(f3.z, f3.w);
    *reinterpret_cast<uint4*>(&A3[row * 136 + p * 16]) = pk0;
    *reinterpret_cast<uint4*>(&A3[row * 136 + p * 16 + 8]) = pk1;
  }
  __syncthreads();
  f32x4 acc[2][2];
  const int j0 = w * 32 + l15, j1 = w * 32 + 16 + l15;
  {
    float v0 = eob[j0], v1 = eob[j1];
    f32x4 t0 = {v0, v0, v0, v0}, t1 = {v1, v1, v1, v1};
    acc[0][0] = t0; acc[1][0] = t0;
    acc[0][1] = t1; acc[1][1] = t1;
  }
#pragma unroll
  for (int ks = 0; ks < 4; ++ks) {
    bf16x8 a0 = ldb8(&A3[l15 * 136 + ks * 32 + lhi * 8]);
    bf16x8 a1 = ldb8(&A3[(16 + l15) * 136 + ks * 32 + lhi * 8]);
    bf16x8 b0 = ldb8(eoWt + (size_t)j0 * 256 + ks * 32 + lhi * 8);
    bf16x8 b1 = ldb8(eoWt + (size_t)j1 * 256 + ks * 32 + lhi * 8);
    acc[0][0] = mfma16(a0, b0, acc[0][0]);
    acc[1][0] = mfma16(a1, b0, acc[1][0]);
    acc[0][1] = mfma16(a0, b1, acc[0][1]);
    acc[1][1] = mfma16(a1, b1, acc[1][1]);
  }
#pragma unroll
  for (int m = 0; m < 2; ++m)
#pragma unroll
    for (int n = 0; n < 2; ++n)
#pragma unroll
      for (int r = 0; r < 4; ++r) {
        const int row = m * 16 + lhi * 4 + r;
        const int j = w * 32 + n * 16 + l15;
        sft[(size_t)(n0 + row) * 128 + j] = acc[m][n][r];
      }
}

// ---------------- T-LSTM: 8 waves x 16 cols, 64 edges/block, 4-group interleave ----------------
__global__ __launch_bounds__(512, 2)
void lstm_kernel(
    const float* __restrict__ e, const float* __restrict__ dtt,
    const float* __restrict__ b_m, const float* __restrict__ bd_m,
    const float* __restrict__ b_a, const float* __restrict__ bd_a,
    const float* __restrict__ attn,
    const int* __restrict__ elen, const int* __restrict__ perm,
    const u16* __restrict__ UWt_m, const u16* __restrict__ UWt_a,
    const u16* __restrict__ WdT_m, const u16* __restrict__ WdT_a,
    u16* __restrict__ e_out, float* __restrict__ aval_g)
{
  const int bid = blockIdx.x;
  const int sel = bid >> 10;             // 0 = message LSTM, 1 = attention LSTM
  const int edge0 = (1023 - (bid & 1023)) * 64;   // longest-first (LPT)
  const u16* UWt = sel ? UWt_a : UWt_m;
  const u16* WdT = sel ? WdT_a : WdT_m;
  const float* bg  = sel ? b_a  : b_m;
  const float* bdp = sel ? bd_a : bd_m;

  __shared__ __align__(16) u16 Abuf[2][64 * 168];
  __shared__ __align__(16) u16 Cbuf[2][64 * 136];
  __shared__ __align__(16) u16 Eo[64 * 136];
  __shared__ float dec_all[16][64];
  __shared__ int rowedge[64], elen_s[64], tmax_s;

  const int tid = threadIdx.x;
  const int ww = tid >> 6, lane = tid & 63, l15 = lane & 15, lhi = lane >> 4;
  const int j = ww * 16 + l15;
  const int srow = tid >> 3, sp = tid & 7;

  if (tid < 64) {
    int ed = perm[edge0 + tid];
    rowedge[tid] = ed;
    elen_s[tid] = min(max(elen[ed], 1), 16);
  }
  for (int i = tid; i < 2 * 64 * 168; i += 512) (&Abuf[0][0])[i] = 0;
  for (int i = tid; i < 2 * 64 * 136; i += 512) (&Cbuf[0][0])[i] = 0;
  __syncthreads();
  if (tid == 0) {
    int mx = 1;
    for (int i = 0; i < 64; ++i) mx = max(mx, elen_s[i]);
    tmax_s = mx;
  }
  for (int i = tid; i < 1024; i += 512) {
    int row = i & 63, t = i >> 6;
    dec_all[t][row] =
        1.f / logf(2.7182818284590452f + dtt[(size_t)rowedge[row] * 16 + t]);
  }
  {
    float2 e2 = *reinterpret_cast<const float2*>(e + (size_t)rowedge[srow] * 256 + sp * 2);
    *reinterpret_cast<u32*>(&Abuf[0][srow * 168 + 128 + sp * 2]) = cvtpk2(e2.x, e2.y);
  }

  // ---- persistent weight fragments (prescaled): 24 frags = 96 VGPRs/wave ----
  bf16x8 BU[5][4];
#pragma unroll
  for (int ks = 0; ks < 5; ++ks)
#pragma unroll
    for (int g = 0; g < 4; ++g)
      BU[ks][g] = ldb8(UWt + (size_t)(g * 128 + j) * 160 + ks * 32 + lhi * 8);
  bf16x8 BD[4];
#pragma unroll
  for (int ks = 0; ks < 4; ++ks)
    BD[ks] = ldb8(WdT + (size_t)j * 128 + ks * 32 + lhi * 8);
#pragma unroll
  for (int ks = 0; ks < 5; ++ks)
#pragma unroll
    for (int g = 0; g < 4; ++g)
      asm volatile("" : "+v"(BU[ks][g]));
#pragma unroll
  for (int ks = 0; ks < 4; ++ks)
    asm volatile("" : "+v"(BD[ks]));

  f32x4 bias4[4];
#pragma unroll
  for (int g = 0; g < 4; ++g) {
    float b = bg[g * 128 + j] * ((g < 3) ? NL2E : NL2E2);
    f32x4 t = {b, b, b, b};
    bias4[g] = t;
  }
  f32x4 bds4;
  {
    float b = bdp[j] * NL2E2;
    f32x4 t = {b, b, b, b};
    bds4 = t;
  }

  float cst[4][4];
#pragma unroll
  for (int mt = 0; mt < 4; ++mt)
#pragma unroll
    for (int r = 0; r < 4; ++r) cst[mt][r] = 0.f;
  __syncthreads();
  const int tmax = tmax_s;

  for (int t = 0; t < tmax; ++t) {
    const u16* Ar = Abuf[t & 1];
    const u16* Cr = Cbuf[t & 1];
    u16* Aw = Abuf[(t + 1) & 1];
    u16* Cw = Cbuf[(t + 1) & 1];

    // T14 split: issue next e_t load early; LDS-write after all groups' phase B
    float2 e2n;
    const bool stage_next = (t + 1 < tmax);
    if (stage_next)
      e2n = *reinterpret_cast<const float2*>(
          e + (size_t)rowedge[srow] * 256 + (t + 1) * 16 + sp * 2);

    // ---- four 16-edge groups: A(G) then B(G); barrier only at step end.
    // B(Gi) writes Aw rows of group i; A(Gk>i) reads Ar rows of group k -> disjoint.
#pragma unroll
    for (int mt = 0; mt < 4; ++mt) {
      f32x4 acc[4];
      f32x4 accs1;
      {
        bf16x8 a = ldb8(&Ar[(mt * 16 + l15) * 168 + lhi * 8]);
#pragma unroll
        for (int g = 0; g < 4; ++g)
          acc[g] = mfma16(a, BU[0][g], bias4[g]);
      }
#pragma unroll
      for (int ks = 1; ks < 5; ++ks) {
        bf16x8 a = ldb8(&Ar[(mt * 16 + l15) * 168 + ks * 32 + lhi * 8]);
#pragma unroll
        for (int g = 0; g < 4; ++g)
          acc[g] = mfma16(a, BU[ks][g], acc[g]);
      }
      {
        bf16x8 c = ldb8(&Cr[(mt * 16 + l15) * 136 + lhi * 8]);
        accs1 = mfma16(c, BD[0], bds4);
      }
#pragma unroll
      for (int ks = 1; ks < 4; ++ks) {
        bf16x8 c = ldb8(&Cr[(mt * 16 + l15) * 136 + ks * 32 + lhi * 8]);
        accs1 = mfma16(c, BD[ks], accs1);
      }
      // phase B for this group
#pragma unroll
      for (int r = 0; r < 4; ++r) {
        const int row = mt * 16 + lhi * 4 + r;
        float iv = rcp_(1.f + ex2(acc[0][r]));
        float fv = rcp_(1.f + ex2(acc[1][r]));
        float ov = rcp_(1.f + ex2(acc[2][r]));
        float gv = 2.f * rcp_(1.f + ex2(acc[3][r])) - 1.f;
        float cs = 2.f * rcp_(1.f + ex2(accs1[r])) - 1.f;
        float dec = dec_all[t][row];
        float co = cst[mt][r];
        float cstar = co + cs * (dec - 1.f);   // c - c_s + c_s*dec
        float cn = fv * cstar + iv * gv;
        float th = 2.f * rcp_(1.f + ex2(cn * NL2E2)) - 1.f;
        float hn = ov * th;
        cst[mt][r] = cn;
        u16 hb = f2bf_h(hn);
        Aw[row * 168 + j] = hb;
        Cw[row * 136 + j] = f2bf_h(cn);
        if (elen_s[row] == t + 1) Eo[row * 136 + j] = hb;
      }
    }
    if (stage_next)
      *reinterpret_cast<u32*>(&Aw[srow * 168 + 128 + sp * 2]) = cvtpk2(e2n.x, e2n.y);
    __syncthreads();   // single barrier per step
  }

  if (sel) {   // attention logit
    if (tid < 64) {
      float s = 0.f;
      for (int k = 0; k < 128; ++k) s += bf2f(Eo[tid * 136 + k]) * attn[k];
      aval_g[rowedge[tid]] = s > 0.f ? s : 0.01f * s;
    }
  } else {     // e_out writeback
    uint4 v0 = *reinterpret_cast<const uint4*>(&Eo[srow * 136 + sp * 16]);
    uint4 v1 = *reinterpret_cast<const uint4*>(&Eo[srow * 136 + sp * 16 + 8]);
    u16* dst = e_out + (size_t)rowedge[srow] * 128 + sp * 16;
    *reinterpret_cast<uint4*>(dst) = v0;
    *reinterpret_cast<uint4*>(dst + 8) = v1;
  }
}

// ---------------- node mid: edge GEMM + sparsemax + aggregate -> hagg bf16 ----------------
__global__ __launch_bounds__(256) void node_mid(
    const float* __restrict__ nf, const u16* __restrict__ e_out,
    const float* __restrict__ aval_g, const float* __restrict__ eob,
    const int* __restrict__ srci, const u16* __restrict__ eoWt,
    const float* __restrict__ sft, u16* __restrict__ haggb)
{
  const int node = blockIdx.x;
  const int tid = threadIdx.x;
  const int ebase = node * 32;
  const int w = tid >> 6, lane = tid & 63, l15 = lane & 15, lhi = lane >> 4;

  __shared__ __align__(16) u16 A2[32 * 264];
  __shared__ __align__(16) u16 Msh[32 * 136];
  __shared__ float aval[32], zsrc[32], zs[32], redf[32], alpha_s[32];
  __shared__ int redi[32];

  {
    const int row = tid >> 3, p = tid & 7;
    const int src = srci[ebase + row];
    const float4* ph = reinterpret_cast<const float4*>(nf + (size_t)src * 128 + p * 16);
    float4 f0 = ph[0], f1 = ph[1], f2 = ph[2], f3 = ph[3];
    uint4 pk0, pk1;
    pk0.x = cvtpk2(f0.x, f0.y); pk0.y = cvtpk2(f0.z, f0.w);
    pk0.z = cvtpk2(f1.x, f1.y); pk0.w = cvtpk2(f1.z, f1.w);
    pk1.x = cvtpk2(f2.x, f2.y); pk1.y = cvtpk2(f2.z, f2.w);
    pk1.z = cvtpk2(f3.x, f3.y); pk1.w = cvtpk2(f3.z, f3.w);
    *reinterpret_cast<uint4*>(&A2[row * 264 + p * 16]) = pk0;
    *reinterpret_cast<uint4*>(&A2[row * 264 + p * 16 + 8]) = pk1;
    const u16* pe = e_out + (size_t)(ebase + row) * 128 + p * 16;
    *reinterpret_cast<uint4*>(&A2[row * 264 + 128 + p * 16]) =
        *reinterpret_cast<const uint4*>(pe);
    *reinterpret_cast<uint4*>(&A2[row * 264 + 128 + p * 16 + 8]) =
        *reinterpret_cast<const uint4*>(pe + 8);
  }
  if (tid < 32) aval[tid] = aval_g[ebase + tid];
  __syncthreads();

  {
    f32x4 eacc[2][2];
    const int j0 = w * 32 + l15, j1 = w * 32 + 16 + l15;
    {
      float v0 = eob[j0], v1 = eob[j1];
      f32x4 t0 = {v0, v0, v0, v0}, t1 = {v1, v1, v1, v1};
      eacc[0][0] = t0; eacc[1][0] = t0;
      eacc[0][1] = t1; eacc[1][1] = t1;
    }
#pragma unroll
    for (int ks = 0; ks < 8; ++ks) {
      bf16x8 a0 = ldb8(&A2[l15 * 264 + ks * 32 + lhi * 8]);
      bf16x8 a1 = ldb8(&A2[(16 + l15) * 264 + ks * 32 + lhi * 8]);
      bf16x8 b0 = ldb8(eoWt + (size_t)j0 * 256 + ks * 32 + lhi * 8);
      bf16x8 b1 = ldb8(eoWt + (size_t)j1 * 256 + ks * 32 + lhi * 8);
      eacc[0][0] = mfma16(a0, b0, eacc[0][0]);
      eacc[1][0] = mfma16(a1, b0, eacc[1][0]);
      eacc[0][1] = mfma16(a0, b1, eacc[0][1]);
      eacc[1][1] = mfma16(a1, b1, eacc[1][1]);
    }
#pragma unroll
    for (int m = 0; m < 2; ++m)
#pragma unroll
      for (int n = 0; n < 2; ++n)
#pragma unroll
        for (int r = 0; r < 4; ++r) {
          const int row = m * 16 + lhi * 4 + r;
          const int jj = w * 32 + n * 16 + l15;
          Msh[row * 136 + jj] = f2bf_h(fmaxf(eacc[m][n][r], 0.f));
        }
  }
  __syncthreads();

  if (tid < 32) {
    float mx = -1e30f;
    for (int jj = 0; jj < 32; ++jj) mx = fmaxf(mx, aval[jj]);
    float z = aval[tid] - mx;
    zsrc[tid] = z;
    int rank = 0;
    for (int jj = 0; jj < 32; ++jj) {
      float zj = aval[jj] - mx;
      rank += (zj > z) || (zj == z && jj < tid);
    }
    zs[rank] = z;
  }
  __syncthreads();
  if (tid < 32) {
    float cum = 0.f;
    for (int s = 0; s <= tid; ++s) cum += zs[s];
    float zst = zs[tid];
    bool isg = (1.f + (float)(tid + 1) * zst) > cum;
    redf[tid] = isg ? zst : 0.f;
    redi[tid] = isg ? (tid + 1) : 0;
  }
  __syncthreads();
  if (tid < 32) {
    int kk = 0; float ss = 0.f;
    for (int jj = 0; jj < 32; ++jj) { kk = max(kk, redi[jj]); ss += redf[jj]; }
    float tau = (ss - 1.f) / (float)kk;
    alpha_s[tid] = fmaxf(0.f, zsrc[tid] - tau);
  }
  __syncthreads();

  if (tid < 128) {
    float s = 0.f;
    for (int d = 0; d < 32; ++d) s += alpha_s[d] * bf2f(Msh[d * 136 + tid]);
    haggb[(size_t)node * 128 + tid] = f2bf_h(s - sft[(size_t)node * 128 + tid]);
  }
}

// ---------------- post: acts = relu([selfh|hagg]@ndW + ndb); out = acts@fcW + fcb ----------------
__global__ __launch_bounds__(256) void post_gemm(
    const float* __restrict__ nf, const u16* __restrict__ haggb,
    const float* __restrict__ ndb, const u16* __restrict__ ndWt,
    const float* __restrict__ fcb, const u16* __restrict__ fcWt,
    float* __restrict__ out)
{
  const int n0 = blockIdx.x * 32;
  const int tid = threadIdx.x;
  const int w = tid >> 6, lane = tid & 63, l15 = lane & 15, lhi = lane >> 4;
  __shared__ __align__(16) u16 A3[32 * 264];
  __shared__ __align__(16) u16 Acts[32 * 136];

  {
    const int row = tid >> 3, p = tid & 7;
    const float4* ph = reinterpret_cast<const float4*>(nf + (size_t)(n0 + row) * 128 + p * 16);
    float4 f0 = ph[0], f1 = ph[1], f2 = ph[2], f3 = ph[3];
    uint4 pk0, pk1;
    pk0.x = cvtpk2(f0.x, f0.y); pk0.y = cvtpk2(f0.z, f0.w);
    pk0.z = cvtpk2(f1.x, f1.y); pk0.w = cvtpk2(f1.z, f1.w);
    pk1.x = cvtpk2(f2.x, f2.y); pk1.y = cvtpk2(f2.z, f2.w);
    pk1.z = cvtpk2(f3.x, f3.y); pk1.w = cvtpk2(f3.z, f3.w);
    *reinterpret_cast<uint4*>(&A3[row * 264 + p * 16]) = pk0;
    *reinterpret_cast<uint4*>(&A3[row * 264 + p * 16 + 8]) = pk1;
    const u16* pg = haggb + (size_t)(n0 + row) * 128 + p * 16;
    *reinterpret_cast<uint4*>(&A3[row * 264 + 128 + p * 16]) =
        *reinterpret_cast<const uint4*>(pg);
    *reinterpret_cast<uint4*>(&A3[row * 264 + 128 + p * 16 + 8]) =
        *reinterpret_cast<const uint4*>(pg + 8);
  }
  __syncthreads();

  {
    f32x4 acc[2][2];
    const int j0 = w * 32 + l15, j1 = w * 32 + 16 + l15;
    {
      float v0 = ndb[j0], v1 = ndb[j1];
      f32x4 t0 = {v0, v0, v0, v0}, t1 = {v1, v1, v1, v1};
      acc[0][0] = t0; acc[1][0] = t0;
      acc[0][1] = t1; acc[1][1] = t1;
    }
#pragma unroll
    for (int ks = 0; ks < 8; ++ks) {
      bf16x8 a0 = ldb8(&A3[l15 * 264 + ks * 32 + lhi * 8]);
      bf16x8 a1 = ldb8(&A3[(16 + l15) * 264 + ks * 32 + lhi * 8]);
      bf16x8 b0 = ldb8(ndWt + (size_t)j0 * 256 + ks * 32 + lhi * 8);
      bf16x8 b1 = ldb8(ndWt + (size_t)j1 * 256 + ks * 32 + lhi * 8);
      acc[0][0] = mfma16(a0, b0, acc[0][0]);
      acc[1][0] = mfma16(a1, b0, acc[1][0]);
      acc[0][1] = mfma16(a0, b1, acc[0][1]);
      acc[1][1] = mfma16(a1, b1, acc[1][1]);
    }
#pragma unroll
    for (int m = 0; m < 2; ++m)
#pragma unroll
      for (int n = 0; n < 2; ++n)
#pragma unroll
        for (int r = 0; r < 4; ++r) {
          const int row = m * 16 + lhi * 4 + r;
          const int jj = w * 32 + n * 16 + l15;
          Acts[row * 136 + jj] = f2bf_h(fmaxf(acc[m][n][r], 0.f));
        }
  }
  __syncthreads();

  if (w < 2) {
    const int m = w;
    f32x4 acc1;
    {
      float v = (l15 < 10) ? fcb[l15] : 0.f;
      f32x4 t = {v, v, v, v};
      acc1 = t;
    }
#pragma unroll
    for (int ks = 0; ks < 4; ++ks) {
      bf16x8 a = ldb8(&Acts[(m * 16 + l15) * 136 + ks * 32 + lhi * 8]);
      bf16x8 b = ldb8(fcWt + (size_t)l15 * 128 + ks * 32 + lhi * 8);
      acc1 = mfma16(a, b, acc1);
    }
    if (l15 < 10) {
#pragma unroll
      for (int r = 0; r < 4; ++r) {
        const int row = m * 16 + lhi * 4 + r;
        out[(size_t)(n0 + row) * 10 + l15] = acc1[r];
      }
    }
  }
}

extern "C" void kernel_launch(void* const* d_in, const int* in_sizes, int n_in,
                              void* d_out, int out_size, void* d_ws, size_t ws_size,
                              hipStream_t stream)
{
  const float* nf   = (const float*)d_in[0];
  const float* e    = (const float*)d_in[1];
  const float* dtt  = (const float*)d_in[2];
  const float* W_m  = (const float*)d_in[3];
  const float* U_m  = (const float*)d_in[4];
  const float* b_m  = (const float*)d_in[5];
  const float* Wd_m = (const float*)d_in[6];
  const float* bd_m = (const float*)d_in[7];
  const float* W_a  = (const float*)d_in[8];
  const float* U_a  = (const float*)d_in[9];
  const float* b_a  = (const float*)d_in[10];
  const float* Wd_a = (const float*)d_in[11];
  const float* bd_a = (const float*)d_in[12];
  const float* attn = (const float*)d_in[13];
  const float* eoW  = (const float*)d_in[14];
  const float* eob  = (const float*)d_in[15];
  const float* ndW  = (const float*)d_in[16];
  const float* ndb  = (const float*)d_in[17];
  const float* fcW  = (const float*)d_in[18];
  const float* fcb  = (const float*)d_in[19];
  const int* elen = (const int*)d_in[20];
  const int* srci = (const int*)d_in[21];

  char* ws = (char*)d_ws;
  u16* UWt_m  = (u16*)(ws + 0);
  u16* UWt_a  = (u16*)(ws + 163840);
  u16* WdT_m  = (u16*)(ws + 327680);
  u16* WdT_a  = (u16*)(ws + 360448);
  u16* eoWt   = (u16*)(ws + 393216);          // ends 458752
  u16* e_out  = (u16*)(ws + 458752);          // 16 MB
  float* aval = (float*)(ws + 17235968);      // 256 KB
  int* perm   = (int*)(ws + 17498112);        // 256 KB
  int* cnt    = (int*)(ws + 17760256);
  int* coff   = (int*)(ws + 17760320);
  u16* ndWt   = (u16*)(ws + 17760384);        // 64 KB
  u16* fcWt   = (u16*)(ws + 17825920);        // 4 KB
  float* sft  = (float*)(ws + 17830016);      // 1 MB
  u16* haggb  = (u16*)(ws + 18878592);        // 512 KB

  hipMemsetAsync(cnt, 0, 64, stream);
  prep_kernel<<<1032, 256, 0, stream>>>(U_m, W_m, U_a, W_a, Wd_m, Wd_a, eoW, ndW, fcW,
                                        UWt_m, UWt_a, WdT_m, WdT_a, eoWt, ndWt, fcWt);
  hist_kernel<<<EDGES / 256, 256, 0, stream>>>(elen, cnt);
  scan_kernel<<<1, 1, 0, stream>>>(cnt, coff);
  scatter_kernel<<<EDGES / 256, 256, 0, stream>>>(elen, coff, perm);
  pre_gemm<<<NDST / 32, 256, 0, stream>>>(nf, eob, eoWt, sft);
  lstm_kernel<<<2048, 512, 0, stream>>>(e, dtt, b_m, bd_m, b_a, bd_a, attn,
                                        elen, perm, UWt_m, UWt_a, WdT_m, WdT_a,
                                        e_out, aval);
  node_mid<<<NDST, 256, 0, stream>>>(nf, e_out, aval, eob, srci, eoWt, sft, haggb);
  post_gemm<<<NDST / 32, 256, 0, stream>>>(nf, haggb, ndb, ndWt, fcb, fcWt,
                                           (float*)d_out);
}